// Round 8
// baseline (1113.026 us; speedup 1.0000x reference)
//
#include <hip/hip_runtime.h>
#include <hip/hip_bf16.h>
#include <stdint.h>

typedef __bf16 bf16_t;
typedef bf16_t bf16x8 __attribute__((ext_vector_type(8)));
typedef float f32x4 __attribute__((ext_vector_type(4)));

#define N_NODES 10000
#define N_EDGES 160000
#define IN_DIM 128
#define HID 512
#define LN_EPS 1e-5f
#define BK 32

#define AS1 __attribute__((address_space(1)))
#define AS3 __attribute__((address_space(3)))

static __device__ __forceinline__ void gload_lds16(const void* g, void* l) {
  __builtin_amdgcn_global_load_lds((const AS1 void*)g, (AS3 void*)l, 16, 0, 0);
}

// ---------------- small utility kernels ----------------

__global__ void k_cast(const float* __restrict__ s, bf16_t* __restrict__ d, int n) {
  int i = blockIdx.x * 256 + threadIdx.x;
  if (i < n) d[i] = (bf16_t)s[i];
}

// LDS-tiled transpose+cast: dst[N][K] = bf16(src[K][N]); grid (N/32, K/32), 256 thr
__global__ __launch_bounds__(256) void k_tpose(const float* __restrict__ src,
                                               bf16_t* __restrict__ dst, int K, int N) {
  __shared__ float t[32][33];
  int cx = threadIdx.x & 31, ry = threadIdx.x >> 5;  // 0..31, 0..7
  int n0 = blockIdx.x * 32, k0 = blockIdx.y * 32;
#pragma unroll
  for (int i = 0; i < 32; i += 8)
    t[ry + i][cx] = src[(size_t)(k0 + ry + i) * N + n0 + cx];
  __syncthreads();
#pragma unroll
  for (int i = 0; i < 32; i += 8)
    dst[(size_t)(n0 + ry + i) * K + k0 + cx] = (bf16_t)t[cx][ry + i];
}

__global__ void k_deg_init(float* deg) {
  int i = blockIdx.x * 256 + threadIdx.x;
  if (i < N_NODES) deg[i] = 1.0f;  // self-loop
}
__global__ void k_deg_count(const int* __restrict__ col, float* deg) {
  int e = blockIdx.x * 256 + threadIdx.x;
  if (e < N_EDGES) atomicAdd(&deg[col[e]], 1.0f);
}
__global__ void k_dis(const float* __restrict__ deg, float* __restrict__ dis) {
  int i = blockIdx.x * 256 + threadIdx.x;
  if (i < N_NODES) dis[i] = rsqrtf(deg[i]);  // deg >= 1 always
}

// ---------------- CSR builds ----------------

__global__ void k_zero2(int* a, int* b) {
  int i = blockIdx.x * 256 + threadIdx.x;
  if (i < N_NODES) { a[i] = 0; b[i] = 0; }
}
__global__ void k_cnt(const int* __restrict__ key, int* cnt) {
  int e = blockIdx.x * 256 + threadIdx.x;
  if (e < N_EDGES) atomicAdd(&cnt[key[e]], 1);
}
// single-block exclusive scan: rowptr[0..N_NODES]
__global__ __launch_bounds__(256) void k_scan(const int* __restrict__ cnt,
                                              int* __restrict__ rowptr) {
  __shared__ int part[256];
  __shared__ int pref[257];
  int tid = threadIdx.x;
  const int CH = 40;  // 256*40 >= 10001
  int s = 0;
  for (int i = 0; i < CH; ++i) {
    int idx = tid * CH + i;
    if (idx < N_NODES) s += cnt[idx];
  }
  part[tid] = s;
  __syncthreads();
  if (tid == 0) {
    int a = 0;
    for (int i = 0; i < 256; ++i) { pref[i] = a; a += part[i]; }
    pref[256] = a;
  }
  __syncthreads();
  int a = pref[tid];
  for (int i = 0; i < CH; ++i) {
    int idx = tid * CH + i;
    if (idx < N_NODES) {
      rowptr[idx] = a;
      a += cnt[idx];
    } else if (idx == N_NODES) {
      rowptr[idx] = a;
    }
  }
}
// target-CSR fill (aggregation): src + weight per slot
__global__ void k_fill(const int* __restrict__ ei, const float* __restrict__ dis,
                       const int* __restrict__ rowptr, int* __restrict__ cursor,
                       int* __restrict__ esrc, float* __restrict__ ew) {
  int e = blockIdx.x * 256 + threadIdx.x;
  if (e >= N_EDGES) return;
  int s = ei[e];
  int t = ei[N_EDGES + e];
  int pos = atomicAdd(&cursor[t], 1);
  int o = rowptr[t] + pos;
  esrc[o] = s;
  ew[o] = dis[s] * dis[t];
}
// source-sorted edge list for the MLP (u-gather locality) + output permutation
__global__ void k_fill2(const int* __restrict__ ei, const int* __restrict__ rowptr,
                        int* __restrict__ cursor, int* __restrict__ esrc2,
                        int* __restrict__ edst2, int* __restrict__ eperm) {
  int e = blockIdx.x * 256 + threadIdx.x;
  if (e >= N_EDGES) return;
  int s = ei[e];
  int t = ei[N_EDGES + e];
  int pos = atomicAdd(&cursor[s], 1);
  int o = rowptr[s] + pos;
  esrc2[o] = s;
  edst2[o] = t;
  eperm[o] = e;
}

// ---------------- fused aggregation + ReLU + LayerNorm (T in bf16) ----------------
__global__ __launch_bounds__(256) void k_agg_ln(
    const bf16_t* __restrict__ T, const int* __restrict__ rowptr,
    const int* __restrict__ esrc, const float* __restrict__ ew,
    const float* __restrict__ dis, const float* __restrict__ bias,
    const float* __restrict__ g, const float* __restrict__ b,
    bf16_t* __restrict__ out) {
  int w = threadIdx.x >> 6, lane = threadIdx.x & 63;
  int node = blockIdx.x * 4 + w;
  if (node >= N_NODES) return;
  int d0 = lane << 3;  // 8 dims per lane
  float dw = dis[node];
  dw *= dw;
  float a[8];
  {
    bf16x8 tn = *(const bf16x8*)(T + (size_t)node * HID + d0);
    const f32x4* bi = (const f32x4*)(bias + d0);
    f32x4 bv0 = bi[0], bv1 = bi[1];
#pragma unroll
    for (int j = 0; j < 4; ++j) a[j] = dw * (float)tn[j] + bv0[j];
#pragma unroll
    for (int j = 0; j < 4; ++j) a[4 + j] = dw * (float)tn[4 + j] + bv1[j];
  }
  int e = rowptr[node], e1 = rowptr[node + 1];
  for (; e + 1 < e1; e += 2) {
    int s0 = esrc[e], s1i = esrc[e + 1];
    float w0 = ew[e], w1 = ew[e + 1];
    bf16x8 t0 = *(const bf16x8*)(T + (size_t)s0 * HID + d0);
    bf16x8 t1 = *(const bf16x8*)(T + (size_t)s1i * HID + d0);
#pragma unroll
    for (int j = 0; j < 8; ++j) a[j] += w0 * (float)t0[j] + w1 * (float)t1[j];
  }
  if (e < e1) {
    int s0 = esrc[e];
    float w0 = ew[e];
    bf16x8 t0 = *(const bf16x8*)(T + (size_t)s0 * HID + d0);
#pragma unroll
    for (int j = 0; j < 8; ++j) a[j] += w0 * (float)t0[j];
  }
  float s1 = 0.f, s2 = 0.f;
#pragma unroll
  for (int j = 0; j < 8; ++j) {
    a[j] = fmaxf(a[j], 0.f);
    s1 += a[j];
    s2 += a[j] * a[j];
  }
#pragma unroll
  for (int off = 32; off > 0; off >>= 1) {
    s1 += __shfl_xor(s1, off);
    s2 += __shfl_xor(s2, off);
  }
  const float invD = 1.0f / (float)HID;
  float mean = s1 * invD;
  float var = s2 * invD - mean * mean;
  float inv = rsqrtf(var + LN_EPS);
  bf16_t ob[8];
#pragma unroll
  for (int j = 0; j < 8; ++j) {
    int d = d0 + j;
    ob[j] = (bf16_t)((a[j] - mean) * inv * g[d] + b[d]);
  }
  *(bf16x8*)(out + (size_t)node * HID + d0) = *(bf16x8*)ob;
}

// ---------------- per-edge: z0 = relu(LN(UV[src][0:1024] + UV[dst][1024:2048] + mb0))
// edges come in src-sorted order -> u-row reuse in L1/L2.
__global__ __launch_bounds__(256) void k_uv_ln(
    const bf16_t* __restrict__ UV, const int* __restrict__ srcI,
    const int* __restrict__ dstI, const float* __restrict__ mb0,
    const float* __restrict__ g, const float* __restrict__ b,
    bf16_t* __restrict__ z0, int rows) {
  int w = threadIdx.x >> 6, lane = threadIdx.x & 63;
  int row = blockIdx.x * 4 + w;
  if (row >= rows) return;
  int s = srcI[row], t = dstI[row];
  int d0 = lane << 4;  // 16 dims per lane
  const bf16_t* up = UV + (size_t)s * 2048 + d0;
  const bf16_t* vp = UV + (size_t)t * 2048 + 1024 + d0;
  bf16x8 u0 = *(const bf16x8*)up;
  bf16x8 u1 = *(const bf16x8*)(up + 8);
  bf16x8 v0 = *(const bf16x8*)vp;
  bf16x8 v1 = *(const bf16x8*)(vp + 8);
  float f[16];
#pragma unroll
  for (int j = 0; j < 8; ++j) {
    f[j] = (float)u0[j] + (float)v0[j] + mb0[d0 + j];
    f[8 + j] = (float)u1[j] + (float)v1[j] + mb0[d0 + 8 + j];
  }
  float s1 = 0.f, s2 = 0.f;
#pragma unroll
  for (int j = 0; j < 16; ++j) { s1 += f[j]; s2 += f[j] * f[j]; }
#pragma unroll
  for (int off = 32; off > 0; off >>= 1) {
    s1 += __shfl_xor(s1, off);
    s2 += __shfl_xor(s2, off);
  }
  const float invD = 1.0f / 1024.0f;
  float mean = s1 * invD;
  float var = s2 * invD - mean * mean;
  float inv = rsqrtf(var + LN_EPS);
  bf16_t o0[8], o1[8];
#pragma unroll
  for (int j = 0; j < 8; ++j) {
    o0[j] = (bf16_t)fmaxf((f[j] - mean) * inv * g[d0 + j] + b[d0 + j], 0.f);
    o1[j] = (bf16_t)fmaxf((f[8 + j] - mean) * inv * g[d0 + 8 + j] + b[d0 + 8 + j], 0.f);
  }
  bf16_t* zp = z0 + (size_t)row * 1024 + d0;
  *(bf16x8*)zp = *(bf16x8*)o0;
  *(bf16x8*)(zp + 8) = *(bf16x8*)o1;
}

// ---------------- streaming GEMM, templated tile, XCD-co-located grid ----------
// C[M x N] = bf16(A @ Bt^T + bias). Grid: x = row-blocks (padded to x8), y = cols.
template <int BMt, int BNt>
__global__ __launch_bounds__(256) void k_gemm(
    const bf16_t* __restrict__ A, const bf16_t* __restrict__ Bt,
    const float* __restrict__ bias, bf16_t* __restrict__ C,
    int M, int N, int K) {
  constexpr int RI = BMt / 32, CJ = BNt / 32;
  constexpr int SA = BMt / 64, SB = BNt / 64;
  constexpr int EA = BMt * BK, EB = BNt * BK;
  __shared__ __align__(16) bf16_t sA[2 * EA];
  __shared__ __align__(16) bf16_t sB[2 * EB];

  int tid = threadIdx.x;
  int row0 = blockIdx.x * BMt, col0 = blockIdx.y * BNt;
  if (row0 >= M) return;  // padded row-blocks
  int lane = tid & 63, w = tid >> 6;
  int quad = lane >> 4, l15 = lane & 15;
  int wr = (w >> 1) * (BMt / 2), wc = (w & 1) * (BNt / 2);

  int rbase = tid >> 2;
  int kchunk = ((tid & 3) - (tid >> 3)) & 3;  // bank-swizzle rotation
  int ksegg = kchunk << 3;

  const bf16_t* pa[SA];
  const bf16_t* pb[SB];
#pragma unroll
  for (int s = 0; s < SA; ++s) {
    int g0 = row0 + rbase + s * 64;
    if (g0 >= M) g0 = M - 1;  // clamp; never stored
    pa[s] = A + (size_t)g0 * K;
  }
#pragma unroll
  for (int s = 0; s < SB; ++s)
    pb[s] = Bt + (size_t)(col0 + rbase + s * 64) * K;

  int ldsb = (tid & ~63) * 8;

  auto stage = [&](int k0, int bsel) {
    int kk = k0 + ksegg;
    bf16_t* dA = sA + bsel * EA + ldsb;
    bf16_t* dB = sB + bsel * EB + ldsb;
#pragma unroll
    for (int s = 0; s < SA; ++s) gload_lds16(pa[s] + kk, dA + s * 2048);
#pragma unroll
    for (int s = 0; s < SB; ++s) gload_lds16(pb[s] + kk, dB + s * 2048);
  };

  f32x4 acc[RI][CJ] = {};

  stage(0, 0);
  int buf = 0;
  for (int k0 = 0; k0 < K; k0 += BK) {
    __syncthreads();
    if (k0 + BK < K) stage(k0 + BK, buf ^ 1);

    int boA = buf * EA, boB = buf * EB;
    bf16x8 af[RI], bfr[CJ];
#pragma unroll
    for (int i = 0; i < RI; ++i) {
      int rr = wr + (i << 4) + l15;
      af[i] = *(const bf16x8*)&sA[boA + rr * BK + (((quad + (rr >> 1)) & 3) << 3)];
    }
#pragma unroll
    for (int j = 0; j < CJ; ++j) {
      int rr = wc + (j << 4) + l15;
      bfr[j] = *(const bf16x8*)&sB[boB + rr * BK + (((quad + (rr >> 1)) & 3) << 3)];
    }
#pragma unroll
    for (int i = 0; i < RI; ++i)
#pragma unroll
      for (int j = 0; j < CJ; ++j)
        acc[i][j] = __builtin_amdgcn_mfma_f32_16x16x32_bf16(af[i], bfr[j], acc[i][j], 0, 0, 0);
    buf ^= 1;
  }

#pragma unroll
  for (int i = 0; i < RI; ++i) {
    int r0e = row0 + wr + (i << 4) + (quad << 2);
#pragma unroll
    for (int j = 0; j < CJ; ++j) {
      int gc = col0 + wc + (j << 4) + l15;
      float bb = bias ? bias[gc] : 0.0f;
#pragma unroll
      for (int r2 = 0; r2 < 4; ++r2) {
        int gr = r0e + r2;
        if (gr < M) C[(size_t)gr * N + gc] = (bf16_t)(acc[i][j][r2] + bb);
      }
    }
  }
}

// ---------------- fused MLP layer-2 + LN + final dot ----------------
// Per 64-edge row block: z1row = z0 @ W1^T + mb1 (full N=512 in-block, fp32),
// then LN(mg1,mbt1), relu, dot(mw2) + mb2 -> out[eperm[row]].
// BM=64, BN=512, BK=32, single-buffered (2-barrier) K-loop.
#define GBM 64
#define GBN 512

__global__ __launch_bounds__(256) void k_gemm2f(
    const bf16_t* __restrict__ A, const bf16_t* __restrict__ Bt,
    const float* __restrict__ mb1, const float* __restrict__ g,
    const float* __restrict__ b, const float* __restrict__ w2,
    const float* __restrict__ mb2, const int* __restrict__ outIdx,
    float* __restrict__ out, int M) {
  constexpr int K = 1024;
  __shared__ __align__(16) bf16_t sA[GBM * BK];   // 4 KB
  __shared__ __align__(16) bf16_t sB[GBN * BK];   // 32 KB
  __shared__ float sC[4][GBN];                    // mb1,g,b,w2: 8 KB
  __shared__ float sS1[2][GBM], sS2[2][GBM], sD[2][GBM];

  int tid = threadIdx.x;
  int row0 = blockIdx.x * GBM;
  int lane = tid & 63, w = tid >> 6;
  int quad = lane >> 4, l15 = lane & 15;
  int wr = (w >> 1) << 5;   // 0 / 32
  int wcHalf = w & 1;
  int wc = wcHalf << 8;     // 0 / 256

  for (int i = tid; i < GBN; i += 256) {
    sC[0][i] = mb1[i]; sC[1][i] = g[i]; sC[2][i] = b[i]; sC[3][i] = w2[i];
  }

  int rbase = tid >> 2;
  int kchunk = ((tid & 3) - (tid >> 3)) & 3;
  int ksegg = kchunk << 3;

  const bf16_t* pa = A + (size_t)(row0 + rbase) * K;
  const bf16_t* pb[8];
#pragma unroll
  for (int s = 0; s < 8; ++s) pb[s] = Bt + (size_t)(rbase + s * 64) * K;

  int ldsb = (tid & ~63) * 8;

  f32x4 acc[2][16] = {};

  for (int k0 = 0; k0 < K; k0 += BK) {
    int kk = k0 + ksegg;
    gload_lds16(pa + kk, sA + ldsb);
#pragma unroll
    for (int s = 0; s < 8; ++s) gload_lds16(pb[s] + kk, sB + ldsb + s * 2048);
    __syncthreads();  // staging complete

    bf16x8 af[2];
#pragma unroll
    for (int i = 0; i < 2; ++i) {
      int rr = wr + (i << 4) + l15;
      af[i] = *(const bf16x8*)&sA[rr * BK + (((quad + (rr >> 1)) & 3) << 3)];
    }
#pragma unroll
    for (int j = 0; j < 16; ++j) {
      int rr = wc + (j << 4) + l15;
      bf16x8 bfr = *(const bf16x8*)&sB[rr * BK + (((quad + (rr >> 1)) & 3) << 3)];
      acc[0][j] = __builtin_amdgcn_mfma_f32_16x16x32_bf16(af[0], bfr, acc[0][j], 0, 0, 0);
      acc[1][j] = __builtin_amdgcn_mfma_f32_16x16x32_bf16(af[1], bfr, acc[1][j], 0, 0, 0);
    }
    __syncthreads();  // reads done before next stage overwrites
  }

  // ---- epilogue: LN stats over this wave's 256-col half ----
#pragma unroll
  for (int i = 0; i < 2; ++i) {
#pragma unroll
    for (int r2 = 0; r2 < 4; ++r2) {
      float a1 = 0.f, a2 = 0.f;
#pragma unroll
      for (int j = 0; j < 16; ++j) {
        int col = wc + (j << 4) + l15;
        float y = acc[i][j][r2] + sC[0][col];
        a1 += y;
        a2 += y * y;
      }
#pragma unroll
      for (int off = 1; off < 16; off <<= 1) {
        a1 += __shfl_xor(a1, off);
        a2 += __shfl_xor(a2, off);
      }
      if (l15 == 0) {
        int row = wr + (i << 4) + (quad << 2) + r2;
        sS1[wcHalf][row] = a1;
        sS2[wcHalf][row] = a2;
      }
    }
  }
  __syncthreads();

  // ---- normalize + relu + dot(w2), combine halves ----
#pragma unroll
  for (int i = 0; i < 2; ++i) {
#pragma unroll
    for (int r2 = 0; r2 < 4; ++r2) {
      int row = wr + (i << 4) + (quad << 2) + r2;
      float t1 = sS1[0][row] + sS1[1][row];
      float t2 = sS2[0][row] + sS2[1][row];
      float mean = t1 * (1.0f / 512.0f);
      float var = t2 * (1.0f / 512.0f) - mean * mean;
      float inv = rsqrtf(var + LN_EPS);
      float d = 0.f;
#pragma unroll
      for (int j = 0; j < 16; ++j) {
        int col = wc + (j << 4) + l15;
        float y = acc[i][j][r2] + sC[0][col];
        y = fmaxf((y - mean) * inv * sC[1][col] + sC[2][col], 0.f);
        d += y * sC[3][col];
      }
#pragma unroll
      for (int off = 1; off < 16; off <<= 1) d += __shfl_xor(d, off);
      if (l15 == 0) sD[wcHalf][row] = d;
    }
  }
  __syncthreads();
  if (tid < GBM) {
    int gr = row0 + tid;
    if (gr < M) out[outIdx[gr]] = sD[0][tid] + sD[1][tid] + mb2[0];
  }
}

// ---------------- host launch ----------------

static inline int pad8(int x) { return (x + 7) & ~7; }

extern "C" void kernel_launch(void* const* d_in, const int* in_sizes, int n_in,
                              void* d_out, int out_size, void* d_ws, size_t ws_size,
                              hipStream_t stream) {
  const float* x = (const float*)d_in[0];
  const int* ei = (const int*)d_in[1];
  const float* w0 = (const float*)d_in[2];
  const float* b0 = (const float*)d_in[3];
  const float* wsL = (const float*)d_in[4];
  const float* bsL = (const float*)d_in[5];
  const float* ln_g = (const float*)d_in[6];
  const float* ln_b = (const float*)d_in[7];
  const float* mw0 = (const float*)d_in[8];
  const float* mb0 = (const float*)d_in[9];
  const float* mg0 = (const float*)d_in[10];
  const float* mbt0 = (const float*)d_in[11];
  const float* mw1 = (const float*)d_in[12];
  const float* mb1 = (const float*)d_in[13];
  const float* mg1 = (const float*)d_in[14];
  const float* mbt1 = (const float*)d_in[15];
  const float* mw2 = (const float*)d_in[16];
  const float* mb2 = (const float*)d_in[17];
  float* out = (float*)d_out;

  char* p = (char*)d_ws;
  auto alloc = [&](size_t bytes) -> void* {
    void* r = (void*)p;
    p += (bytes + 255) & ~(size_t)255;
    return r;
  };
  float* deg = (float*)alloc((size_t)N_NODES * 4);
  float* dis = (float*)alloc((size_t)N_NODES * 4);
  int* cnt = (int*)alloc((size_t)N_NODES * 4);
  int* cursor = (int*)alloc((size_t)N_NODES * 4);
  int* rowptr = (int*)alloc((size_t)(N_NODES + 1) * 4);
  int* esrc = (int*)alloc((size_t)N_EDGES * 4);
  float* ew = (float*)alloc((size_t)N_EDGES * 4);
  int* cnt2 = (int*)alloc((size_t)N_NODES * 4);
  int* cursor2 = (int*)alloc((size_t)N_NODES * 4);
  int* rowptr2 = (int*)alloc((size_t)(N_NODES + 1) * 4);
  int* esrc2 = (int*)alloc((size_t)N_EDGES * 4);
  int* edst2 = (int*)alloc((size_t)N_EDGES * 4);
  int* eperm = (int*)alloc((size_t)N_EDGES * 4);
  bf16_t* xb = (bf16_t*)alloc((size_t)N_NODES * IN_DIM * 2);
  bf16_t* hb0 = (bf16_t*)alloc((size_t)N_NODES * HID * 2);
  bf16_t* hb1 = (bf16_t*)alloc((size_t)N_NODES * HID * 2);
  bf16_t* w0t = (bf16_t*)alloc((size_t)HID * IN_DIM * 2);
  bf16_t* wst = (bf16_t*)alloc((size_t)3 * HID * HID * 2);
  bf16_t* mw0t = (bf16_t*)alloc((size_t)2048 * 512 * 2);  // [W0_top | W0_bot] as Bt
  bf16_t* mw1t = (bf16_t*)alloc((size_t)512 * 1024 * 2);
  bf16_t* UV = (bf16_t*)alloc((size_t)N_NODES * 2048 * 2);  // 41 MB
  size_t fixed = (size_t)(p - (char*)d_ws);

  // overlap pool: GCN-phase T (10.24 MB) vs MLP z0 (2048 B/edge). z1 no longer exists.
  int CE = 16000;
  const int ce_opts[4] = {160000, 80000, 32000, 16000};  // /64 and divide 160000
  for (int i = 0; i < 4; ++i) {
    size_t pool_need = (size_t)ce_opts[i] * 2048;
    size_t tneed = (size_t)N_NODES * HID * 2;
    if (pool_need < tneed) pool_need = tneed;
    if (fixed + pool_need + 4096 <= ws_size) { CE = ce_opts[i]; break; }
  }
  char* pool = p;
  bf16_t* T = (bf16_t*)pool;
  bf16_t* z0 = (bf16_t*)pool;  // aliases T; GCN fully precedes MLP (same stream)

  k_cast<<<(N_NODES * IN_DIM + 255) / 256, 256, 0, stream>>>(x, xb, N_NODES * IN_DIM);
  { dim3 g(HID / 32, IN_DIM / 32);
    k_tpose<<<g, 256, 0, stream>>>(w0, w0t, IN_DIM, HID); }
  for (int i = 0; i < 3; ++i) {
    dim3 g(HID / 32, HID / 32);
    k_tpose<<<g, 256, 0, stream>>>(wsL + (size_t)i * HID * HID,
                                   wst + (size_t)i * HID * HID, HID, HID);
  }
  { dim3 g(1024 / 32, 512 / 32);
    k_tpose<<<g, 256, 0, stream>>>(mw0, mw0t, 512, 1024);                       // top
    k_tpose<<<g, 256, 0, stream>>>(mw0 + (size_t)512 * 1024,
                                   mw0t + (size_t)1024 * 512, 512, 1024); }     // bot
  { dim3 g(512 / 32, 1024 / 32);
    k_tpose<<<g, 256, 0, stream>>>(mw1, mw1t, 1024, 512); }

  k_deg_init<<<(N_NODES + 255) / 256, 256, 0, stream>>>(deg);
  k_deg_count<<<(N_EDGES + 255) / 256, 256, 0, stream>>>(ei + N_EDGES, deg);
  k_dis<<<(N_NODES + 255) / 256, 256, 0, stream>>>(deg, dis);

  // target-CSR (aggregation)
  k_zero2<<<(N_NODES + 255) / 256, 256, 0, stream>>>(cnt, cursor);
  k_cnt<<<(N_EDGES + 255) / 256, 256, 0, stream>>>(ei + N_EDGES, cnt);
  k_scan<<<1, 256, 0, stream>>>(cnt, rowptr);
  k_fill<<<(N_EDGES + 255) / 256, 256, 0, stream>>>(ei, dis, rowptr, cursor, esrc, ew);
  // source-sorted edge list (MLP locality + out permutation)
  k_zero2<<<(N_NODES + 255) / 256, 256, 0, stream>>>(cnt2, cursor2);
  k_cnt<<<(N_EDGES + 255) / 256, 256, 0, stream>>>(ei, cnt2);
  k_scan<<<1, 256, 0, stream>>>(cnt2, rowptr2);
  k_fill2<<<(N_EDGES + 255) / 256, 256, 0, stream>>>(ei, rowptr2, cursor2,
                                                     esrc2, edst2, eperm);

  // ---- 4 GCN layers ----
  int nrb64 = pad8((N_NODES + 63) / 64);  // 157 -> 160
  bf16_t* hbufs[2] = {hb0, hb1};
  for (int L = 0; L < 4; ++L) {
    const bf16_t* Ain = (L == 0) ? xb : hbufs[(L + 1) & 1];
    int K = (L == 0) ? IN_DIM : HID;
    const bf16_t* Bt = (L == 0) ? w0t : wst + (size_t)(L - 1) * HID * HID;
    dim3 grid(nrb64, HID / 128);
    k_gemm<64, 128><<<grid, 256, 0, stream>>>(Ain, Bt, nullptr, T, N_NODES, HID, K);
    const float* bias = (L == 0) ? b0 : bsL + (size_t)(L - 1) * HID;
    k_agg_ln<<<(N_NODES + 3) / 4, 256, 0, stream>>>(
        T, rowptr, esrc, ew, dis, bias, ln_g + (size_t)L * HID,
        ln_b + (size_t)L * HID, hbufs[L & 1]);
  }
  bf16_t* hfin = hbufs[1];

  // ---- node-level UV = hfin @ [W0_top | W0_bot]  (10000 x 2048, K=512) ----
  { dim3 g(nrb64, 2048 / 128);
    k_gemm<64, 128><<<g, 256, 0, stream>>>(hfin, mw0t, nullptr, UV, N_NODES, 2048, 512); }

  // ---- edge MLP, chunked over src-sorted edges ----
  int nchunks = N_EDGES / CE;
  for (int c = 0; c < nchunks; ++c) {
    int e0 = c * CE;
    k_uv_ln<<<CE / 4, 256, 0, stream>>>(UV, esrc2 + e0, edst2 + e0, mb0, mg0, mbt0,
                                        z0, CE);
    k_gemm2f<<<CE / 64, 256, 0, stream>>>(z0, mw1t, mb1, mg1, mbt1, mw2, mb2,
                                          eperm + e0, out, CE);
  }
  (void)in_sizes; (void)n_in; (void)out_size;
}

// Round 9
// 995.327 us; speedup vs baseline: 1.1183x; 1.1183x over previous
//
#include <hip/hip_runtime.h>
#include <hip/hip_bf16.h>
#include <stdint.h>

typedef __bf16 bf16_t;
typedef bf16_t bf16x8 __attribute__((ext_vector_type(8)));
typedef float f32x4 __attribute__((ext_vector_type(4)));

#define N_NODES 10000
#define N_EDGES 160000
#define IN_DIM 128
#define HID 512
#define LN_EPS 1e-5f
#define BK 32

#define AS1 __attribute__((address_space(1)))
#define AS3 __attribute__((address_space(3)))

static __device__ __forceinline__ void gload_lds16(const void* g, void* l) {
  __builtin_amdgcn_global_load_lds((const AS1 void*)g, (AS3 void*)l, 16, 0, 0);
}

// ---------------- small utility kernels ----------------

__global__ void k_cast(const float* __restrict__ s, bf16_t* __restrict__ d, int n) {
  int i = blockIdx.x * 256 + threadIdx.x;
  if (i < n) d[i] = (bf16_t)s[i];
}

// LDS-tiled transpose+cast: dst[N][K] = bf16(src[K][N]); grid (N/32, K/32), 256 thr
__global__ __launch_bounds__(256) void k_tpose(const float* __restrict__ src,
                                               bf16_t* __restrict__ dst, int K, int N) {
  __shared__ float t[32][33];
  int cx = threadIdx.x & 31, ry = threadIdx.x >> 5;  // 0..31, 0..7
  int n0 = blockIdx.x * 32, k0 = blockIdx.y * 32;
#pragma unroll
  for (int i = 0; i < 32; i += 8)
    t[ry + i][cx] = src[(size_t)(k0 + ry + i) * N + n0 + cx];
  __syncthreads();
#pragma unroll
  for (int i = 0; i < 32; i += 8)
    dst[(size_t)(n0 + ry + i) * K + k0 + cx] = (bf16_t)t[cx][ry + i];
}

__global__ void k_deg_init(float* deg) {
  int i = blockIdx.x * 256 + threadIdx.x;
  if (i < N_NODES) deg[i] = 1.0f;  // self-loop
}
__global__ void k_deg_count(const int* __restrict__ col, float* deg) {
  int e = blockIdx.x * 256 + threadIdx.x;
  if (e < N_EDGES) atomicAdd(&deg[col[e]], 1.0f);
}
__global__ void k_dis(const float* __restrict__ deg, float* __restrict__ dis) {
  int i = blockIdx.x * 256 + threadIdx.x;
  if (i < N_NODES) dis[i] = rsqrtf(deg[i]);  // deg >= 1 always
}

// ---------------- CSR builds ----------------

__global__ void k_zero2(int* a, int* b) {
  int i = blockIdx.x * 256 + threadIdx.x;
  if (i < N_NODES) { a[i] = 0; b[i] = 0; }
}
__global__ void k_cnt(const int* __restrict__ key, int* cnt) {
  int e = blockIdx.x * 256 + threadIdx.x;
  if (e < N_EDGES) atomicAdd(&cnt[key[e]], 1);
}
// single-block exclusive scan: rowptr[0..N_NODES]
__global__ __launch_bounds__(256) void k_scan(const int* __restrict__ cnt,
                                              int* __restrict__ rowptr) {
  __shared__ int part[256];
  __shared__ int pref[257];
  int tid = threadIdx.x;
  const int CH = 40;  // 256*40 >= 10001
  int s = 0;
  for (int i = 0; i < CH; ++i) {
    int idx = tid * CH + i;
    if (idx < N_NODES) s += cnt[idx];
  }
  part[tid] = s;
  __syncthreads();
  if (tid == 0) {
    int a = 0;
    for (int i = 0; i < 256; ++i) { pref[i] = a; a += part[i]; }
    pref[256] = a;
  }
  __syncthreads();
  int a = pref[tid];
  for (int i = 0; i < CH; ++i) {
    int idx = tid * CH + i;
    if (idx < N_NODES) {
      rowptr[idx] = a;
      a += cnt[idx];
    } else if (idx == N_NODES) {
      rowptr[idx] = a;
    }
  }
}
// target-CSR fill (aggregation): src + weight per slot
__global__ void k_fill(const int* __restrict__ ei, const float* __restrict__ dis,
                       const int* __restrict__ rowptr, int* __restrict__ cursor,
                       int* __restrict__ esrc, float* __restrict__ ew) {
  int e = blockIdx.x * 256 + threadIdx.x;
  if (e >= N_EDGES) return;
  int s = ei[e];
  int t = ei[N_EDGES + e];
  int pos = atomicAdd(&cursor[t], 1);
  int o = rowptr[t] + pos;
  esrc[o] = s;
  ew[o] = dis[s] * dis[t];
}
// source-sorted edge list for the MLP (u-gather locality) + output permutation
__global__ void k_fill2(const int* __restrict__ ei, const int* __restrict__ rowptr,
                        int* __restrict__ cursor, int* __restrict__ esrc2,
                        int* __restrict__ edst2, int* __restrict__ eperm) {
  int e = blockIdx.x * 256 + threadIdx.x;
  if (e >= N_EDGES) return;
  int s = ei[e];
  int t = ei[N_EDGES + e];
  int pos = atomicAdd(&cursor[s], 1);
  int o = rowptr[s] + pos;
  esrc2[o] = s;
  edst2[o] = t;
  eperm[o] = e;
}

// ---------------- fused aggregation + ReLU + LayerNorm (T in bf16) ----------------
__global__ __launch_bounds__(256) void k_agg_ln(
    const bf16_t* __restrict__ T, const int* __restrict__ rowptr,
    const int* __restrict__ esrc, const float* __restrict__ ew,
    const float* __restrict__ dis, const float* __restrict__ bias,
    const float* __restrict__ g, const float* __restrict__ b,
    bf16_t* __restrict__ out) {
  int w = threadIdx.x >> 6, lane = threadIdx.x & 63;
  int node = blockIdx.x * 4 + w;
  if (node >= N_NODES) return;
  int d0 = lane << 3;  // 8 dims per lane
  float dw = dis[node];
  dw *= dw;
  float a[8];
  {
    bf16x8 tn = *(const bf16x8*)(T + (size_t)node * HID + d0);
    const f32x4* bi = (const f32x4*)(bias + d0);
    f32x4 bv0 = bi[0], bv1 = bi[1];
#pragma unroll
    for (int j = 0; j < 4; ++j) a[j] = dw * (float)tn[j] + bv0[j];
#pragma unroll
    for (int j = 0; j < 4; ++j) a[4 + j] = dw * (float)tn[4 + j] + bv1[j];
  }
  int e = rowptr[node], e1 = rowptr[node + 1];
  for (; e + 1 < e1; e += 2) {
    int s0 = esrc[e], s1i = esrc[e + 1];
    float w0 = ew[e], w1 = ew[e + 1];
    bf16x8 t0 = *(const bf16x8*)(T + (size_t)s0 * HID + d0);
    bf16x8 t1 = *(const bf16x8*)(T + (size_t)s1i * HID + d0);
#pragma unroll
    for (int j = 0; j < 8; ++j) a[j] += w0 * (float)t0[j] + w1 * (float)t1[j];
  }
  if (e < e1) {
    int s0 = esrc[e];
    float w0 = ew[e];
    bf16x8 t0 = *(const bf16x8*)(T + (size_t)s0 * HID + d0);
#pragma unroll
    for (int j = 0; j < 8; ++j) a[j] += w0 * (float)t0[j];
  }
  float s1 = 0.f, s2 = 0.f;
#pragma unroll
  for (int j = 0; j < 8; ++j) {
    a[j] = fmaxf(a[j], 0.f);
    s1 += a[j];
    s2 += a[j] * a[j];
  }
#pragma unroll
  for (int off = 32; off > 0; off >>= 1) {
    s1 += __shfl_xor(s1, off);
    s2 += __shfl_xor(s2, off);
  }
  const float invD = 1.0f / (float)HID;
  float mean = s1 * invD;
  float var = s2 * invD - mean * mean;
  float inv = rsqrtf(var + LN_EPS);
  bf16_t ob[8];
#pragma unroll
  for (int j = 0; j < 8; ++j) {
    int d = d0 + j;
    ob[j] = (bf16_t)((a[j] - mean) * inv * g[d] + b[d]);
  }
  *(bf16x8*)(out + (size_t)node * HID + d0) = *(bf16x8*)ob;
}

// ---------------- per-edge: z0 = relu(LN(UV[src][0:1024] + UV[dst][1024:2048] + mb0))
// edges are src-sorted -> u-row sequential + reused in L1/L2.
__global__ __launch_bounds__(256) void k_uv_ln(
    const bf16_t* __restrict__ UV, const int* __restrict__ srcI,
    const int* __restrict__ dstI, const float* __restrict__ mb0,
    const float* __restrict__ g, const float* __restrict__ b,
    bf16_t* __restrict__ z0, int rows) {
  int w = threadIdx.x >> 6, lane = threadIdx.x & 63;
  int row = blockIdx.x * 4 + w;
  if (row >= rows) return;
  int s = srcI[row], t = dstI[row];
  int d0 = lane << 4;  // 16 dims per lane
  const bf16_t* up = UV + (size_t)s * 2048 + d0;
  const bf16_t* vp = UV + (size_t)t * 2048 + 1024 + d0;
  bf16x8 u0 = *(const bf16x8*)up;
  bf16x8 u1 = *(const bf16x8*)(up + 8);
  bf16x8 v0 = *(const bf16x8*)vp;
  bf16x8 v1 = *(const bf16x8*)(vp + 8);
  float f[16];
#pragma unroll
  for (int j = 0; j < 8; ++j) {
    f[j] = (float)u0[j] + (float)v0[j] + mb0[d0 + j];
    f[8 + j] = (float)u1[j] + (float)v1[j] + mb0[d0 + 8 + j];
  }
  float s1 = 0.f, s2 = 0.f;
#pragma unroll
  for (int j = 0; j < 16; ++j) { s1 += f[j]; s2 += f[j] * f[j]; }
#pragma unroll
  for (int off = 32; off > 0; off >>= 1) {
    s1 += __shfl_xor(s1, off);
    s2 += __shfl_xor(s2, off);
  }
  const float invD = 1.0f / 1024.0f;
  float mean = s1 * invD;
  float var = s2 * invD - mean * mean;
  float inv = rsqrtf(var + LN_EPS);
  bf16_t o0[8], o1[8];
#pragma unroll
  for (int j = 0; j < 8; ++j) {
    o0[j] = (bf16_t)fmaxf((f[j] - mean) * inv * g[d0 + j] + b[d0 + j], 0.f);
    o1[j] = (bf16_t)fmaxf((f[8 + j] - mean) * inv * g[d0 + 8 + j] + b[d0 + 8 + j], 0.f);
  }
  bf16_t* zp = z0 + (size_t)row * 1024 + d0;
  *(bf16x8*)zp = *(bf16x8*)o0;
  *(bf16x8*)(zp + 8) = *(bf16x8*)o1;
}

// wave-per-row: out[outIdx[row]] = dot(relu(LN(z1[row])), mw2) + mb2, D=512
__global__ __launch_bounds__(256) void k_ln_dot(
    const bf16_t* __restrict__ z1, const float* __restrict__ g,
    const float* __restrict__ b, const float* __restrict__ mw2,
    const float* __restrict__ mb2, const int* __restrict__ outIdx,
    float* __restrict__ out, int rows) {
  int w = threadIdx.x >> 6, lane = threadIdx.x & 63;
  int row = blockIdx.x * 4 + w;
  if (row >= rows) return;
  int d0 = lane << 3;
  bf16x8 v = *(const bf16x8*)(z1 + (size_t)row * 512 + d0);
  float f[8];
#pragma unroll
  for (int j = 0; j < 8; ++j) f[j] = (float)v[j];
  float s1 = 0.f, s2 = 0.f;
#pragma unroll
  for (int j = 0; j < 8; ++j) { s1 += f[j]; s2 += f[j] * f[j]; }
#pragma unroll
  for (int off = 32; off > 0; off >>= 1) {
    s1 += __shfl_xor(s1, off);
    s2 += __shfl_xor(s2, off);
  }
  const float invD = 1.0f / 512.0f;
  float mean = s1 * invD;
  float var = s2 * invD - mean * mean;
  float inv = rsqrtf(var + LN_EPS);
  float acc = 0.f;
#pragma unroll
  for (int j = 0; j < 8; ++j) {
    float y = fmaxf((f[j] - mean) * inv * g[d0 + j] + b[d0 + j], 0.f);
    acc += y * mw2[d0 + j];
  }
#pragma unroll
  for (int off = 32; off > 0; off >>= 1) acc += __shfl_xor(acc, off);
  if (lane == 0) out[outIdx[row]] = acc + mb2[0];
}

// ---------------- streaming GEMM, templated tile, XCD-co-located grid ----------
// C[M x N] = bf16(A @ Bt^T + bias). Grid: x = row-blocks (padded to x8), y = cols.
template <int BMt, int BNt>
__global__ __launch_bounds__(256) void k_gemm(
    const bf16_t* __restrict__ A, const bf16_t* __restrict__ Bt,
    const float* __restrict__ bias, bf16_t* __restrict__ C,
    int M, int N, int K) {
  constexpr int RI = BMt / 32, CJ = BNt / 32;
  constexpr int SA = BMt / 64, SB = BNt / 64;
  constexpr int EA = BMt * BK, EB = BNt * BK;
  __shared__ __align__(16) bf16_t sA[2 * EA];
  __shared__ __align__(16) bf16_t sB[2 * EB];

  int tid = threadIdx.x;
  int row0 = blockIdx.x * BMt, col0 = blockIdx.y * BNt;
  if (row0 >= M) return;  // padded row-blocks
  int lane = tid & 63, w = tid >> 6;
  int quad = lane >> 4, l15 = lane & 15;
  int wr = (w >> 1) * (BMt / 2), wc = (w & 1) * (BNt / 2);

  int rbase = tid >> 2;
  int kchunk = ((tid & 3) - (tid >> 3)) & 3;  // bank-swizzle rotation
  int ksegg = kchunk << 3;

  const bf16_t* pa[SA];
  const bf16_t* pb[SB];
#pragma unroll
  for (int s = 0; s < SA; ++s) {
    int g0 = row0 + rbase + s * 64;
    if (g0 >= M) g0 = M - 1;  // clamp; never stored
    pa[s] = A + (size_t)g0 * K;
  }
#pragma unroll
  for (int s = 0; s < SB; ++s)
    pb[s] = Bt + (size_t)(col0 + rbase + s * 64) * K;

  int ldsb = (tid & ~63) * 8;

  auto stage = [&](int k0, int bsel) {
    int kk = k0 + ksegg;
    bf16_t* dA = sA + bsel * EA + ldsb;
    bf16_t* dB = sB + bsel * EB + ldsb;
#pragma unroll
    for (int s = 0; s < SA; ++s) gload_lds16(pa[s] + kk, dA + s * 2048);
#pragma unroll
    for (int s = 0; s < SB; ++s) gload_lds16(pb[s] + kk, dB + s * 2048);
  };

  f32x4 acc[RI][CJ] = {};

  stage(0, 0);
  int buf = 0;
  for (int k0 = 0; k0 < K; k0 += BK) {
    __syncthreads();
    if (k0 + BK < K) stage(k0 + BK, buf ^ 1);

    int boA = buf * EA, boB = buf * EB;
    bf16x8 af[RI], bfr[CJ];
#pragma unroll
    for (int i = 0; i < RI; ++i) {
      int rr = wr + (i << 4) + l15;
      af[i] = *(const bf16x8*)&sA[boA + rr * BK + (((quad + (rr >> 1)) & 3) << 3)];
    }
#pragma unroll
    for (int j = 0; j < CJ; ++j) {
      int rr = wc + (j << 4) + l15;
      bfr[j] = *(const bf16x8*)&sB[boB + rr * BK + (((quad + (rr >> 1)) & 3) << 3)];
    }
#pragma unroll
    for (int i = 0; i < RI; ++i)
#pragma unroll
      for (int j = 0; j < CJ; ++j)
        acc[i][j] = __builtin_amdgcn_mfma_f32_16x16x32_bf16(af[i], bfr[j], acc[i][j], 0, 0, 0);
    buf ^= 1;
  }

#pragma unroll
  for (int i = 0; i < RI; ++i) {
    int r0e = row0 + wr + (i << 4) + (quad << 2);
#pragma unroll
    for (int j = 0; j < CJ; ++j) {
      int gc = col0 + wc + (j << 4) + l15;
      float bb = bias ? bias[gc] : 0.0f;
#pragma unroll
      for (int r2 = 0; r2 < 4; ++r2) {
        int gr = r0e + r2;
        if (gr < M) C[(size_t)gr * N + gc] = (bf16_t)(acc[i][j][r2] + bb);
      }
    }
  }
}

// ---------------- host launch ----------------

static inline int pad8(int x) { return (x + 7) & ~7; }

extern "C" void kernel_launch(void* const* d_in, const int* in_sizes, int n_in,
                              void* d_out, int out_size, void* d_ws, size_t ws_size,
                              hipStream_t stream) {
  const float* x = (const float*)d_in[0];
  const int* ei = (const int*)d_in[1];
  const float* w0 = (const float*)d_in[2];
  const float* b0 = (const float*)d_in[3];
  const float* wsL = (const float*)d_in[4];
  const float* bsL = (const float*)d_in[5];
  const float* ln_g = (const float*)d_in[6];
  const float* ln_b = (const float*)d_in[7];
  const float* mw0 = (const float*)d_in[8];
  const float* mb0 = (const float*)d_in[9];
  const float* mg0 = (const float*)d_in[10];
  const float* mbt0 = (const float*)d_in[11];
  const float* mw1 = (const float*)d_in[12];
  const float* mb1 = (const float*)d_in[13];
  const float* mg1 = (const float*)d_in[14];
  const float* mbt1 = (const float*)d_in[15];
  const float* mw2 = (const float*)d_in[16];
  const float* mb2 = (const float*)d_in[17];
  float* out = (float*)d_out;

  char* p = (char*)d_ws;
  auto alloc = [&](size_t bytes) -> void* {
    void* r = (void*)p;
    p += (bytes + 255) & ~(size_t)255;
    return r;
  };
  float* deg = (float*)alloc((size_t)N_NODES * 4);
  float* dis = (float*)alloc((size_t)N_NODES * 4);
  int* cnt = (int*)alloc((size_t)N_NODES * 4);
  int* cursor = (int*)alloc((size_t)N_NODES * 4);
  int* rowptr = (int*)alloc((size_t)(N_NODES + 1) * 4);
  int* esrc = (int*)alloc((size_t)N_EDGES * 4);
  float* ew = (float*)alloc((size_t)N_EDGES * 4);
  int* cnt2 = (int*)alloc((size_t)N_NODES * 4);
  int* cursor2 = (int*)alloc((size_t)N_NODES * 4);
  int* rowptr2 = (int*)alloc((size_t)(N_NODES + 1) * 4);
  int* esrc2 = (int*)alloc((size_t)N_EDGES * 4);
  int* edst2 = (int*)alloc((size_t)N_EDGES * 4);
  int* eperm = (int*)alloc((size_t)N_EDGES * 4);
  bf16_t* xb = (bf16_t*)alloc((size_t)N_NODES * IN_DIM * 2);
  bf16_t* hb0 = (bf16_t*)alloc((size_t)N_NODES * HID * 2);
  bf16_t* hb1 = (bf16_t*)alloc((size_t)N_NODES * HID * 2);
  bf16_t* w0t = (bf16_t*)alloc((size_t)HID * IN_DIM * 2);
  bf16_t* wst = (bf16_t*)alloc((size_t)3 * HID * HID * 2);
  bf16_t* mw0t = (bf16_t*)alloc((size_t)2048 * 512 * 2);  // [W0_top | W0_bot] as Bt
  bf16_t* mw1t = (bf16_t*)alloc((size_t)512 * 1024 * 2);
  bf16_t* UV = (bf16_t*)alloc((size_t)N_NODES * 2048 * 2);  // 41 MB
  size_t fixed = (size_t)(p - (char*)d_ws);

  // overlap pool: GCN-phase T (10.24 MB) vs MLP z0 (2048 B/edge) + z1 (1024 B/edge)
  int CE = 16000;
  const int ce_opts[3] = {80000, 32000, 16000};  // multiples of 128, divide 160000
  for (int i = 0; i < 3; ++i) {
    size_t pool_need = (size_t)ce_opts[i] * 3072;
    size_t tneed = (size_t)N_NODES * HID * 2;
    if (pool_need < tneed) pool_need = tneed;
    if (fixed + pool_need + 4096 <= ws_size) { CE = ce_opts[i]; break; }
  }
  char* pool = p;
  bf16_t* T = (bf16_t*)pool;
  bf16_t* z0 = (bf16_t*)pool;  // aliases T; GCN fully precedes MLP (same stream)
  bf16_t* z1 = (bf16_t*)(pool + (size_t)CE * 2048);

  k_cast<<<(N_NODES * IN_DIM + 255) / 256, 256, 0, stream>>>(x, xb, N_NODES * IN_DIM);
  { dim3 g(HID / 32, IN_DIM / 32);
    k_tpose<<<g, 256, 0, stream>>>(w0, w0t, IN_DIM, HID); }
  for (int i = 0; i < 3; ++i) {
    dim3 g(HID / 32, HID / 32);
    k_tpose<<<g, 256, 0, stream>>>(wsL + (size_t)i * HID * HID,
                                   wst + (size_t)i * HID * HID, HID, HID);
  }
  { dim3 g(1024 / 32, 512 / 32);
    k_tpose<<<g, 256, 0, stream>>>(mw0, mw0t, 512, 1024);                       // top
    k_tpose<<<g, 256, 0, stream>>>(mw0 + (size_t)512 * 1024,
                                   mw0t + (size_t)1024 * 512, 512, 1024); }     // bot
  { dim3 g(512 / 32, 1024 / 32);
    k_tpose<<<g, 256, 0, stream>>>(mw1, mw1t, 1024, 512); }

  k_deg_init<<<(N_NODES + 255) / 256, 256, 0, stream>>>(deg);
  k_deg_count<<<(N_EDGES + 255) / 256, 256, 0, stream>>>(ei + N_EDGES, deg);
  k_dis<<<(N_NODES + 255) / 256, 256, 0, stream>>>(deg, dis);

  // target-CSR (aggregation)
  k_zero2<<<(N_NODES + 255) / 256, 256, 0, stream>>>(cnt, cursor);
  k_cnt<<<(N_EDGES + 255) / 256, 256, 0, stream>>>(ei + N_EDGES, cnt);
  k_scan<<<1, 256, 0, stream>>>(cnt, rowptr);
  k_fill<<<(N_EDGES + 255) / 256, 256, 0, stream>>>(ei, dis, rowptr, cursor, esrc, ew);
  // source-sorted edge list (MLP locality + out permutation)
  k_zero2<<<(N_NODES + 255) / 256, 256, 0, stream>>>(cnt2, cursor2);
  k_cnt<<<(N_EDGES + 255) / 256, 256, 0, stream>>>(ei, cnt2);
  k_scan<<<1, 256, 0, stream>>>(cnt2, rowptr2);
  k_fill2<<<(N_EDGES + 255) / 256, 256, 0, stream>>>(ei, rowptr2, cursor2,
                                                     esrc2, edst2, eperm);

  // ---- 4 GCN layers ----
  int nrb64 = pad8((N_NODES + 63) / 64);  // 157 -> 160
  bf16_t* hbufs[2] = {hb0, hb1};
  for (int L = 0; L < 4; ++L) {
    const bf16_t* Ain = (L == 0) ? xb : hbufs[(L + 1) & 1];
    int K = (L == 0) ? IN_DIM : HID;
    const bf16_t* Bt = (L == 0) ? w0t : wst + (size_t)(L - 1) * HID * HID;
    dim3 grid(nrb64, HID / 128);
    k_gemm<64, 128><<<grid, 256, 0, stream>>>(Ain, Bt, nullptr, T, N_NODES, HID, K);
    const float* bias = (L == 0) ? b0 : bsL + (size_t)(L - 1) * HID;
    k_agg_ln<<<(N_NODES + 3) / 4, 256, 0, stream>>>(
        T, rowptr, esrc, ew, dis, bias, ln_g + (size_t)L * HID,
        ln_b + (size_t)L * HID, hbufs[L & 1]);
  }
  bf16_t* hfin = hbufs[1];

  // ---- node-level UV = hfin @ [W0_top | W0_bot]  (10000 x 2048, K=512) ----
  { dim3 g(nrb64, 2048 / 128);
    k_gemm<64, 128><<<g, 256, 0, stream>>>(hfin, mw0t, nullptr, UV, N_NODES, 2048, 512); }

  // ---- edge MLP, chunked over src-sorted edges ----
  int nchunks = N_EDGES / CE;
  for (int c = 0; c < nchunks; ++c) {
    int e0 = c * CE;
    k_uv_ln<<<CE / 4, 256, 0, stream>>>(UV, esrc2 + e0, edst2 + e0, mb0, mg0, mbt0,
                                        z0, CE);
    dim3 g2(pad8(CE / 128), HID / 128);
    k_gemm<128, 128><<<g2, 256, 0, stream>>>(z0, mw1t, mb1, z1, CE, HID, 1024);
    k_ln_dot<<<CE / 4, 256, 0, stream>>>(z1, mg1, mbt1, mw2, mb2, eperm + e0,
                                         out, CE);
  }
  (void)in_sizes; (void)n_in; (void)out_size;
}

// Round 10
// 943.295 us; speedup vs baseline: 1.1799x; 1.0552x over previous
//
#include <hip/hip_runtime.h>
#include <hip/hip_bf16.h>
#include <stdint.h>

typedef __bf16 bf16_t;
typedef bf16_t bf16x8 __attribute__((ext_vector_type(8)));
typedef float f32x4 __attribute__((ext_vector_type(4)));

#define N_NODES 10000
#define N_EDGES 160000
#define IN_DIM 128
#define HID 512
#define LN_EPS 1e-5f
#define BK 32

#define AS1 __attribute__((address_space(1)))
#define AS3 __attribute__((address_space(3)))

static __device__ __forceinline__ void gload_lds16(const void* g, void* l) {
  __builtin_amdgcn_global_load_lds((const AS1 void*)g, (AS3 void*)l, 16, 0, 0);
}

// ---------------- small utility kernels ----------------

__global__ void k_cast(const float* __restrict__ s, bf16_t* __restrict__ d, int n) {
  int i = blockIdx.x * 256 + threadIdx.x;
  if (i < n) d[i] = (bf16_t)s[i];
}

// LDS-tiled transpose+cast: dst[N][K] = bf16(src[K][N]); grid (N/32, K/32), 256 thr
__global__ __launch_bounds__(256) void k_tpose(const float* __restrict__ src,
                                               bf16_t* __restrict__ dst, int K, int N) {
  __shared__ float t[32][33];
  int cx = threadIdx.x & 31, ry = threadIdx.x >> 5;  // 0..31, 0..7
  int n0 = blockIdx.x * 32, k0 = blockIdx.y * 32;
#pragma unroll
  for (int i = 0; i < 32; i += 8)
    t[ry + i][cx] = src[(size_t)(k0 + ry + i) * N + n0 + cx];
  __syncthreads();
#pragma unroll
  for (int i = 0; i < 32; i += 8)
    dst[(size_t)(n0 + ry + i) * K + k0 + cx] = (bf16_t)t[cx][ry + i];
}

// ---------------- CSR build (edges keyed by target) + degree norm ----------------

__global__ void k_zero2(int* a, int* b) {
  int i = blockIdx.x * 256 + threadIdx.x;
  if (i < N_NODES) { a[i] = 0; b[i] = 0; }
}
__global__ void k_cnt(const int* __restrict__ key, int* cnt) {
  int e = blockIdx.x * 256 + threadIdx.x;
  if (e < N_EDGES) atomicAdd(&cnt[key[e]], 1);
}
// dis = rsqrt(deg), deg = in-degree + 1 self-loop = cnt + 1
__global__ void k_dis(const int* __restrict__ cnt, float* __restrict__ dis) {
  int i = blockIdx.x * 256 + threadIdx.x;
  if (i < N_NODES) dis[i] = rsqrtf(1.0f + (float)cnt[i]);
}
// single-block exclusive scan: rowptr[0..N_NODES]
__global__ __launch_bounds__(256) void k_scan(const int* __restrict__ cnt,
                                              int* __restrict__ rowptr) {
  __shared__ int part[256];
  __shared__ int pref[257];
  int tid = threadIdx.x;
  const int CH = 40;  // 256*40 >= 10001
  int s = 0;
  for (int i = 0; i < CH; ++i) {
    int idx = tid * CH + i;
    if (idx < N_NODES) s += cnt[idx];
  }
  part[tid] = s;
  __syncthreads();
  if (tid == 0) {
    int a = 0;
    for (int i = 0; i < 256; ++i) { pref[i] = a; a += part[i]; }
    pref[256] = a;
  }
  __syncthreads();
  int a = pref[tid];
  for (int i = 0; i < CH; ++i) {
    int idx = tid * CH + i;
    if (idx < N_NODES) {
      rowptr[idx] = a;
      a += cnt[idx];
    } else if (idx == N_NODES) {
      rowptr[idx] = a;
    }
  }
}
// target-CSR fill (aggregation): src + weight per slot
__global__ void k_fill(const int* __restrict__ ei, const float* __restrict__ dis,
                       const int* __restrict__ rowptr, int* __restrict__ cursor,
                       int* __restrict__ esrc, float* __restrict__ ew) {
  int e = blockIdx.x * 256 + threadIdx.x;
  if (e >= N_EDGES) return;
  int s = ei[e];
  int t = ei[N_EDGES + e];
  int pos = atomicAdd(&cursor[t], 1);
  int o = rowptr[t] + pos;
  esrc[o] = s;
  ew[o] = dis[s] * dis[t];
}

// ---------------- fused aggregation + ReLU + LayerNorm (T in bf16) ----------------
__global__ __launch_bounds__(256) void k_agg_ln(
    const bf16_t* __restrict__ T, const int* __restrict__ rowptr,
    const int* __restrict__ esrc, const float* __restrict__ ew,
    const float* __restrict__ dis, const float* __restrict__ bias,
    const float* __restrict__ g, const float* __restrict__ b,
    bf16_t* __restrict__ out) {
  int w = threadIdx.x >> 6, lane = threadIdx.x & 63;
  int node = blockIdx.x * 4 + w;
  if (node >= N_NODES) return;
  int d0 = lane << 3;  // 8 dims per lane
  float dw = dis[node];
  dw *= dw;
  float a[8];
  {
    bf16x8 tn = *(const bf16x8*)(T + (size_t)node * HID + d0);
    const f32x4* bi = (const f32x4*)(bias + d0);
    f32x4 bv0 = bi[0], bv1 = bi[1];
#pragma unroll
    for (int j = 0; j < 4; ++j) a[j] = dw * (float)tn[j] + bv0[j];
#pragma unroll
    for (int j = 0; j < 4; ++j) a[4 + j] = dw * (float)tn[4 + j] + bv1[j];
  }
  int e = rowptr[node], e1 = rowptr[node + 1];
  for (; e + 1 < e1; e += 2) {
    int s0 = esrc[e], s1i = esrc[e + 1];
    float w0 = ew[e], w1 = ew[e + 1];
    bf16x8 t0 = *(const bf16x8*)(T + (size_t)s0 * HID + d0);
    bf16x8 t1 = *(const bf16x8*)(T + (size_t)s1i * HID + d0);
#pragma unroll
    for (int j = 0; j < 8; ++j) a[j] += w0 * (float)t0[j] + w1 * (float)t1[j];
  }
  if (e < e1) {
    int s0 = esrc[e];
    float w0 = ew[e];
    bf16x8 t0 = *(const bf16x8*)(T + (size_t)s0 * HID + d0);
#pragma unroll
    for (int j = 0; j < 8; ++j) a[j] += w0 * (float)t0[j];
  }
  float s1 = 0.f, s2 = 0.f;
#pragma unroll
  for (int j = 0; j < 8; ++j) {
    a[j] = fmaxf(a[j], 0.f);
    s1 += a[j];
    s2 += a[j] * a[j];
  }
#pragma unroll
  for (int off = 32; off > 0; off >>= 1) {
    s1 += __shfl_xor(s1, off);
    s2 += __shfl_xor(s2, off);
  }
  const float invD = 1.0f / (float)HID;
  float mean = s1 * invD;
  float var = s2 * invD - mean * mean;
  float inv = rsqrtf(var + LN_EPS);
  bf16_t ob[8];
#pragma unroll
  for (int j = 0; j < 8; ++j) {
    int d = d0 + j;
    ob[j] = (bf16_t)((a[j] - mean) * inv * g[d] + b[d]);
  }
  *(bf16x8*)(out + (size_t)node * HID + d0) = *(bf16x8*)ob;
}

// ---------------- per-edge: z0 = relu(LN(UV[src][0:1024] + UV[dst][1024:2048] + mb0))
__global__ __launch_bounds__(256) void k_uv_ln(
    const bf16_t* __restrict__ UV, const int* __restrict__ srcI,
    const int* __restrict__ dstI, const float* __restrict__ mb0,
    const float* __restrict__ g, const float* __restrict__ b,
    bf16_t* __restrict__ z0, int rows) {
  int w = threadIdx.x >> 6, lane = threadIdx.x & 63;
  int row = blockIdx.x * 4 + w;
  if (row >= rows) return;
  int s = srcI[row], t = dstI[row];
  int d0 = lane << 4;  // 16 dims per lane
  const bf16_t* up = UV + (size_t)s * 2048 + d0;
  const bf16_t* vp = UV + (size_t)t * 2048 + 1024 + d0;
  bf16x8 u0 = *(const bf16x8*)up;
  bf16x8 u1 = *(const bf16x8*)(up + 8);
  bf16x8 v0 = *(const bf16x8*)vp;
  bf16x8 v1 = *(const bf16x8*)(vp + 8);
  float f[16];
#pragma unroll
  for (int j = 0; j < 8; ++j) {
    f[j] = (float)u0[j] + (float)v0[j] + mb0[d0 + j];
    f[8 + j] = (float)u1[j] + (float)v1[j] + mb0[d0 + 8 + j];
  }
  float s1 = 0.f, s2 = 0.f;
#pragma unroll
  for (int j = 0; j < 16; ++j) { s1 += f[j]; s2 += f[j] * f[j]; }
#pragma unroll
  for (int off = 32; off > 0; off >>= 1) {
    s1 += __shfl_xor(s1, off);
    s2 += __shfl_xor(s2, off);
  }
  const float invD = 1.0f / 1024.0f;
  float mean = s1 * invD;
  float var = s2 * invD - mean * mean;
  float inv = rsqrtf(var + LN_EPS);
  bf16_t o0[8], o1[8];
#pragma unroll
  for (int j = 0; j < 8; ++j) {
    o0[j] = (bf16_t)fmaxf((f[j] - mean) * inv * g[d0 + j] + b[d0 + j], 0.f);
    o1[j] = (bf16_t)fmaxf((f[8 + j] - mean) * inv * g[d0 + 8 + j] + b[d0 + 8 + j], 0.f);
  }
  bf16_t* zp = z0 + (size_t)row * 1024 + d0;
  *(bf16x8*)zp = *(bf16x8*)o0;
  *(bf16x8*)(zp + 8) = *(bf16x8*)o1;
}

// wave-per-row: out[row] = dot(relu(LN(z1[row])), mw2) + mb2, D=512
__global__ __launch_bounds__(256) void k_ln_dot(
    const bf16_t* __restrict__ z1, const float* __restrict__ g,
    const float* __restrict__ b, const float* __restrict__ mw2,
    const float* __restrict__ mb2, float* __restrict__ out, int rows) {
  int w = threadIdx.x >> 6, lane = threadIdx.x & 63;
  int row = blockIdx.x * 4 + w;
  if (row >= rows) return;
  int d0 = lane << 3;
  bf16x8 v = *(const bf16x8*)(z1 + (size_t)row * 512 + d0);
  float f[8];
#pragma unroll
  for (int j = 0; j < 8; ++j) f[j] = (float)v[j];
  float s1 = 0.f, s2 = 0.f;
#pragma unroll
  for (int j = 0; j < 8; ++j) { s1 += f[j]; s2 += f[j] * f[j]; }
#pragma unroll
  for (int off = 32; off > 0; off >>= 1) {
    s1 += __shfl_xor(s1, off);
    s2 += __shfl_xor(s2, off);
  }
  const float invD = 1.0f / 512.0f;
  float mean = s1 * invD;
  float var = s2 * invD - mean * mean;
  float inv = rsqrtf(var + LN_EPS);
  float acc = 0.f;
#pragma unroll
  for (int j = 0; j < 8; ++j) {
    float y = fmaxf((f[j] - mean) * inv * g[d0 + j] + b[d0 + j], 0.f);
    acc += y * mw2[d0 + j];
  }
#pragma unroll
  for (int off = 32; off > 0; off >>= 1) acc += __shfl_xor(acc, off);
  if (lane == 0) out[row] = acc + mb2[0];
}

// ---------------- streaming GEMM, single-buffered, XCD-co-located grid ----------
// C[M x N] = bf16(A @ Bt^T + bias). Grid: x = row-blocks (padded to x8), y = cols.
// Single-buffer LDS (12/16 KB) -> up to 7-8 resident blocks/CU; at this shape the
// K-loop is staging-latency-bound and residency divides the exposed latency
// (dbuf at 32 KB capped residency at 5 and measured slower — r9 post-mortem).
template <int BMt, int BNt>
__global__ __launch_bounds__(256) void k_gemm(
    const bf16_t* __restrict__ A, const bf16_t* __restrict__ Bt,
    const float* __restrict__ bias, bf16_t* __restrict__ C,
    int M, int N, int K) {
  constexpr int RI = BMt / 32, CJ = BNt / 32;
  constexpr int SA = BMt / 64, SB = BNt / 64;
  __shared__ __align__(16) bf16_t sA[BMt * BK];
  __shared__ __align__(16) bf16_t sB[BNt * BK];

  int tid = threadIdx.x;
  int row0 = blockIdx.x * BMt, col0 = blockIdx.y * BNt;
  if (row0 >= M) return;  // padded row-blocks
  int lane = tid & 63, w = tid >> 6;
  int quad = lane >> 4, l15 = lane & 15;
  int wr = (w >> 1) * (BMt / 2), wc = (w & 1) * (BNt / 2);

  int rbase = tid >> 2;
  int kchunk = ((tid & 3) - (tid >> 3)) & 3;  // bank-swizzle rotation
  int ksegg = kchunk << 3;

  const bf16_t* pa[SA];
  const bf16_t* pb[SB];
#pragma unroll
  for (int s = 0; s < SA; ++s) {
    int g0 = row0 + rbase + s * 64;
    if (g0 >= M) g0 = M - 1;  // clamp; never stored
    pa[s] = A + (size_t)g0 * K;
  }
#pragma unroll
  for (int s = 0; s < SB; ++s)
    pb[s] = Bt + (size_t)(col0 + rbase + s * 64) * K;

  int ldsb = (tid & ~63) * 8;

  f32x4 acc[RI][CJ] = {};

  for (int k0 = 0; k0 < K; k0 += BK) {
    int kk = k0 + ksegg;
#pragma unroll
    for (int s = 0; s < SA; ++s) gload_lds16(pa[s] + kk, sA + ldsb + s * 2048);
#pragma unroll
    for (int s = 0; s < SB; ++s) gload_lds16(pb[s] + kk, sB + ldsb + s * 2048);
    __syncthreads();  // drains lds-DMA (vmcnt) before fragment reads

    bf16x8 af[RI], bfr[CJ];
#pragma unroll
    for (int i = 0; i < RI; ++i) {
      int rr = wr + (i << 4) + l15;
      af[i] = *(const bf16x8*)&sA[rr * BK + (((quad + (rr >> 1)) & 3) << 3)];
    }
#pragma unroll
    for (int j = 0; j < CJ; ++j) {
      int rr = wc + (j << 4) + l15;
      bfr[j] = *(const bf16x8*)&sB[rr * BK + (((quad + (rr >> 1)) & 3) << 3)];
    }
#pragma unroll
    for (int i = 0; i < RI; ++i)
#pragma unroll
      for (int j = 0; j < CJ; ++j)
        acc[i][j] = __builtin_amdgcn_mfma_f32_16x16x32_bf16(af[i], bfr[j], acc[i][j], 0, 0, 0);
    __syncthreads();  // reads done before next stage overwrites
  }

  // epilogue: C/D layout col=lane&15, row=quad*4+reg (verified m89/m91)
#pragma unroll
  for (int i = 0; i < RI; ++i) {
    int r0e = row0 + wr + (i << 4) + (quad << 2);
#pragma unroll
    for (int j = 0; j < CJ; ++j) {
      int gc = col0 + wc + (j << 4) + l15;
      float bb = bias ? bias[gc] : 0.0f;
#pragma unroll
      for (int r2 = 0; r2 < 4; ++r2) {
        int gr = r0e + r2;
        if (gr < M) C[(size_t)gr * N + gc] = (bf16_t)(acc[i][j][r2] + bb);
      }
    }
  }
}

// ---------------- host launch ----------------

static inline int pad8(int x) { return (x + 7) & ~7; }

extern "C" void kernel_launch(void* const* d_in, const int* in_sizes, int n_in,
                              void* d_out, int out_size, void* d_ws, size_t ws_size,
                              hipStream_t stream) {
  const float* x = (const float*)d_in[0];
  const int* ei = (const int*)d_in[1];
  const float* w0 = (const float*)d_in[2];
  const float* b0 = (const float*)d_in[3];
  const float* wsL = (const float*)d_in[4];
  const float* bsL = (const float*)d_in[5];
  const float* ln_g = (const float*)d_in[6];
  const float* ln_b = (const float*)d_in[7];
  const float* mw0 = (const float*)d_in[8];
  const float* mb0 = (const float*)d_in[9];
  const float* mg0 = (const float*)d_in[10];
  const float* mbt0 = (const float*)d_in[11];
  const float* mw1 = (const float*)d_in[12];
  const float* mb1 = (const float*)d_in[13];
  const float* mg1 = (const float*)d_in[14];
  const float* mbt1 = (const float*)d_in[15];
  const float* mw2 = (const float*)d_in[16];
  const float* mb2 = (const float*)d_in[17];
  float* out = (float*)d_out;

  char* p = (char*)d_ws;
  auto alloc = [&](size_t bytes) -> void* {
    void* r = (void*)p;
    p += (bytes + 255) & ~(size_t)255;
    return r;
  };
  float* dis = (float*)alloc((size_t)N_NODES * 4);
  int* cnt = (int*)alloc((size_t)N_NODES * 4);
  int* cursor = (int*)alloc((size_t)N_NODES * 4);
  int* rowptr = (int*)alloc((size_t)(N_NODES + 1) * 4);
  int* esrc = (int*)alloc((size_t)N_EDGES * 4);
  float* ew = (float*)alloc((size_t)N_EDGES * 4);
  bf16_t* xb = (bf16_t*)alloc((size_t)N_NODES * IN_DIM * 2);
  bf16_t* hb0 = (bf16_t*)alloc((size_t)N_NODES * HID * 2);
  bf16_t* hb1 = (bf16_t*)alloc((size_t)N_NODES * HID * 2);
  bf16_t* w0t = (bf16_t*)alloc((size_t)HID * IN_DIM * 2);
  bf16_t* wst = (bf16_t*)alloc((size_t)3 * HID * HID * 2);
  bf16_t* mw0t = (bf16_t*)alloc((size_t)2048 * 512 * 2);  // [W0_top | W0_bot] as Bt
  bf16_t* mw1t = (bf16_t*)alloc((size_t)512 * 1024 * 2);
  bf16_t* UV = (bf16_t*)alloc((size_t)N_NODES * 2048 * 2);  // 41 MB
  size_t fixed = (size_t)(p - (char*)d_ws);

  // overlap pool: GCN-phase T (10.24 MB) vs MLP z0 (2048 B/edge) + z1 (1024 B/edge)
  int CE = 16000;
  const int ce_opts[3] = {80000, 32000, 16000};  // multiples of 128, divide 160000
  for (int i = 0; i < 3; ++i) {
    size_t pool_need = (size_t)ce_opts[i] * 3072;
    size_t tneed = (size_t)N_NODES * HID * 2;
    if (pool_need < tneed) pool_need = tneed;
    if (fixed + pool_need + 4096 <= ws_size) { CE = ce_opts[i]; break; }
  }
  char* pool = p;
  bf16_t* T = (bf16_t*)pool;
  bf16_t* z0 = (bf16_t*)pool;  // aliases T; GCN fully precedes MLP (same stream)
  bf16_t* z1 = (bf16_t*)(pool + (size_t)CE * 2048);

  k_cast<<<(N_NODES * IN_DIM + 255) / 256, 256, 0, stream>>>(x, xb, N_NODES * IN_DIM);
  { dim3 g(HID / 32, IN_DIM / 32);
    k_tpose<<<g, 256, 0, stream>>>(w0, w0t, IN_DIM, HID); }
  for (int i = 0; i < 3; ++i) {
    dim3 g(HID / 32, HID / 32);
    k_tpose<<<g, 256, 0, stream>>>(wsL + (size_t)i * HID * HID,
                                   wst + (size_t)i * HID * HID, HID, HID);
  }
  { dim3 g(1024 / 32, 512 / 32);
    k_tpose<<<g, 256, 0, stream>>>(mw0, mw0t, 512, 1024);                       // top
    k_tpose<<<g, 256, 0, stream>>>(mw0 + (size_t)512 * 1024,
                                   mw0t + (size_t)1024 * 512, 512, 1024); }     // bot
  { dim3 g(512 / 32, 1024 / 32);
    k_tpose<<<g, 256, 0, stream>>>(mw1, mw1t, 1024, 512); }

  // CSR + degree norm (deg == cnt + 1, so one count serves both)
  k_zero2<<<(N_NODES + 255) / 256, 256, 0, stream>>>(cnt, cursor);
  k_cnt<<<(N_EDGES + 255) / 256, 256, 0, stream>>>(ei + N_EDGES, cnt);
  k_dis<<<(N_NODES + 255) / 256, 256, 0, stream>>>(cnt, dis);
  k_scan<<<1, 256, 0, stream>>>(cnt, rowptr);
  k_fill<<<(N_EDGES + 255) / 256, 256, 0, stream>>>(ei, dis, rowptr, cursor, esrc, ew);

  // ---- 4 GCN layers ----
  int nrb64 = pad8((N_NODES + 63) / 64);  // 157 -> 160
  bf16_t* hbufs[2] = {hb0, hb1};
  for (int L = 0; L < 4; ++L) {
    const bf16_t* Ain = (L == 0) ? xb : hbufs[(L + 1) & 1];
    int K = (L == 0) ? IN_DIM : HID;
    const bf16_t* Bt = (L == 0) ? w0t : wst + (size_t)(L - 1) * HID * HID;
    dim3 grid(nrb64, HID / 128);
    k_gemm<64, 128><<<grid, 256, 0, stream>>>(Ain, Bt, nullptr, T, N_NODES, HID, K);
    const float* bias = (L == 0) ? b0 : bsL + (size_t)(L - 1) * HID;
    k_agg_ln<<<(N_NODES + 3) / 4, 256, 0, stream>>>(
        T, rowptr, esrc, ew, dis, bias, ln_g + (size_t)L * HID,
        ln_b + (size_t)L * HID, hbufs[L & 1]);
  }
  bf16_t* hfin = hbufs[1];

  // ---- node-level UV = hfin @ [W0_top | W0_bot]  (10000 x 2048, K=512) ----
  { dim3 g(nrb64, 2048 / 128);
    k_gemm<64, 128><<<g, 256, 0, stream>>>(hfin, mw0t, nullptr, UV, N_NODES, 2048, 512); }

  // ---- edge MLP, chunked ----
  int nchunks = N_EDGES / CE;
  for (int c = 0; c < nchunks; ++c) {
    int e0 = c * CE;
    k_uv_ln<<<CE / 4, 256, 0, stream>>>(UV, ei + e0, ei + N_EDGES + e0, mb0, mg0,
                                        mbt0, z0, CE);
    dim3 g2(pad8(CE / 128), HID / 128);
    k_gemm<128, 128><<<g2, 256, 0, stream>>>(z0, mw1t, mb1, z1, CE, HID, 1024);
    k_ln_dot<<<CE / 4, 256, 0, stream>>>(z1, mg1, mbt1, mw2, mb2, out + e0, CE);
  }
  (void)in_sizes; (void)n_in; (void)out_size;
}

// Round 11
// 905.121 us; speedup vs baseline: 1.2297x; 1.0422x over previous
//
#include <hip/hip_runtime.h>
#include <hip/hip_bf16.h>
#include <stdint.h>

typedef __bf16 bf16_t;
typedef bf16_t bf16x8 __attribute__((ext_vector_type(8)));
typedef float f32x4 __attribute__((ext_vector_type(4)));

#define N_NODES 10000
#define N_EDGES 160000
#define IN_DIM 128
#define HID 512
#define LN_EPS 1e-5f
#define BK 64  // 128 B per tile row: 8 x 16B chunks

#define AS1 __attribute__((address_space(1)))
#define AS3 __attribute__((address_space(3)))

static __device__ __forceinline__ void gload_lds16(const void* g, void* l) {
  __builtin_amdgcn_global_load_lds((const AS1 void*)g, (AS3 void*)l, 16, 0, 0);
}

// ---------------- small utility kernels ----------------

__global__ void k_cast(const float* __restrict__ s, bf16_t* __restrict__ d, int n) {
  int i = blockIdx.x * 256 + threadIdx.x;
  if (i < n) d[i] = (bf16_t)s[i];
}

// LDS-tiled transpose+cast: dst[N][K] = bf16(src[K][N]); grid (N/32, K/32), 256 thr
__global__ __launch_bounds__(256) void k_tpose(const float* __restrict__ src,
                                               bf16_t* __restrict__ dst, int K, int N) {
  __shared__ float t[32][33];
  int cx = threadIdx.x & 31, ry = threadIdx.x >> 5;  // 0..31, 0..7
  int n0 = blockIdx.x * 32, k0 = blockIdx.y * 32;
#pragma unroll
  for (int i = 0; i < 32; i += 8)
    t[ry + i][cx] = src[(size_t)(k0 + ry + i) * N + n0 + cx];
  __syncthreads();
#pragma unroll
  for (int i = 0; i < 32; i += 8)
    dst[(size_t)(n0 + ry + i) * K + k0 + cx] = (bf16_t)t[cx][ry + i];
}

// ---------------- CSR build (edges keyed by target) + degree norm ----------------

__global__ void k_zero2(int* a, int* b) {
  int i = blockIdx.x * 256 + threadIdx.x;
  if (i < N_NODES) { a[i] = 0; b[i] = 0; }
}
__global__ void k_cnt(const int* __restrict__ key, int* cnt) {
  int e = blockIdx.x * 256 + threadIdx.x;
  if (e < N_EDGES) atomicAdd(&cnt[key[e]], 1);
}
// dis = rsqrt(deg), deg = in-degree + 1 self-loop = cnt + 1
__global__ void k_dis(const int* __restrict__ cnt, float* __restrict__ dis) {
  int i = blockIdx.x * 256 + threadIdx.x;
  if (i < N_NODES) dis[i] = rsqrtf(1.0f + (float)cnt[i]);
}
// single-block exclusive scan: rowptr[0..N_NODES]
__global__ __launch_bounds__(256) void k_scan(const int* __restrict__ cnt,
                                              int* __restrict__ rowptr) {
  __shared__ int part[256];
  __shared__ int pref[257];
  int tid = threadIdx.x;
  const int CH = 40;  // 256*40 >= 10001
  int s = 0;
  for (int i = 0; i < CH; ++i) {
    int idx = tid * CH + i;
    if (idx < N_NODES) s += cnt[idx];
  }
  part[tid] = s;
  __syncthreads();
  if (tid == 0) {
    int a = 0;
    for (int i = 0; i < 256; ++i) { pref[i] = a; a += part[i]; }
    pref[256] = a;
  }
  __syncthreads();
  int a = pref[tid];
  for (int i = 0; i < CH; ++i) {
    int idx = tid * CH + i;
    if (idx < N_NODES) {
      rowptr[idx] = a;
      a += cnt[idx];
    } else if (idx == N_NODES) {
      rowptr[idx] = a;
    }
  }
}
// target-CSR fill (aggregation): src + weight per slot
__global__ void k_fill(const int* __restrict__ ei, const float* __restrict__ dis,
                       const int* __restrict__ rowptr, int* __restrict__ cursor,
                       int* __restrict__ esrc, float* __restrict__ ew) {
  int e = blockIdx.x * 256 + threadIdx.x;
  if (e >= N_EDGES) return;
  int s = ei[e];
  int t = ei[N_EDGES + e];
  int pos = atomicAdd(&cursor[t], 1);
  int o = rowptr[t] + pos;
  esrc[o] = s;
  ew[o] = dis[s] * dis[t];
}

// ---------------- fused aggregation + ReLU + LayerNorm (T in bf16) ----------------
__global__ __launch_bounds__(256) void k_agg_ln(
    const bf16_t* __restrict__ T, const int* __restrict__ rowptr,
    const int* __restrict__ esrc, const float* __restrict__ ew,
    const float* __restrict__ dis, const float* __restrict__ bias,
    const float* __restrict__ g, const float* __restrict__ b,
    bf16_t* __restrict__ out) {
  int w = threadIdx.x >> 6, lane = threadIdx.x & 63;
  int node = blockIdx.x * 4 + w;
  if (node >= N_NODES) return;
  int d0 = lane << 3;  // 8 dims per lane
  float dw = dis[node];
  dw *= dw;
  float a[8];
  {
    bf16x8 tn = *(const bf16x8*)(T + (size_t)node * HID + d0);
    const f32x4* bi = (const f32x4*)(bias + d0);
    f32x4 bv0 = bi[0], bv1 = bi[1];
#pragma unroll
    for (int j = 0; j < 4; ++j) a[j] = dw * (float)tn[j] + bv0[j];
#pragma unroll
    for (int j = 0; j < 4; ++j) a[4 + j] = dw * (float)tn[4 + j] + bv1[j];
  }
  int e = rowptr[node], e1 = rowptr[node + 1];
  for (; e + 1 < e1; e += 2) {
    int s0 = esrc[e], s1i = esrc[e + 1];
    float w0 = ew[e], w1 = ew[e + 1];
    bf16x8 t0 = *(const bf16x8*)(T + (size_t)s0 * HID + d0);
    bf16x8 t1 = *(const bf16x8*)(T + (size_t)s1i * HID + d0);
#pragma unroll
    for (int j = 0; j < 8; ++j) a[j] += w0 * (float)t0[j] + w1 * (float)t1[j];
  }
  if (e < e1) {
    int s0 = esrc[e];
    float w0 = ew[e];
    bf16x8 t0 = *(const bf16x8*)(T + (size_t)s0 * HID + d0);
#pragma unroll
    for (int j = 0; j < 8; ++j) a[j] += w0 * (float)t0[j];
  }
  float s1 = 0.f, s2 = 0.f;
#pragma unroll
  for (int j = 0; j < 8; ++j) {
    a[j] = fmaxf(a[j], 0.f);
    s1 += a[j];
    s2 += a[j] * a[j];
  }
#pragma unroll
  for (int off = 32; off > 0; off >>= 1) {
    s1 += __shfl_xor(s1, off);
    s2 += __shfl_xor(s2, off);
  }
  const float invD = 1.0f / (float)HID;
  float mean = s1 * invD;
  float var = s2 * invD - mean * mean;
  float inv = rsqrtf(var + LN_EPS);
  bf16_t ob[8];
#pragma unroll
  for (int j = 0; j < 8; ++j) {
    int d = d0 + j;
    ob[j] = (bf16_t)((a[j] - mean) * inv * g[d] + b[d]);
  }
  *(bf16x8*)(out + (size_t)node * HID + d0) = *(bf16x8*)ob;
}

// ---------------- per-edge: z0 = relu(LN(UV[src][0:1024] + UV[dst][1024:2048] + mb0))
__global__ __launch_bounds__(256) void k_uv_ln(
    const bf16_t* __restrict__ UV, const int* __restrict__ srcI,
    const int* __restrict__ dstI, const float* __restrict__ mb0,
    const float* __restrict__ g, const float* __restrict__ b,
    bf16_t* __restrict__ z0, int rows) {
  int w = threadIdx.x >> 6, lane = threadIdx.x & 63;
  int row = blockIdx.x * 4 + w;
  if (row >= rows) return;
  int s = srcI[row], t = dstI[row];
  int d0 = lane << 4;  // 16 dims per lane
  const bf16_t* up = UV + (size_t)s * 2048 + d0;
  const bf16_t* vp = UV + (size_t)t * 2048 + 1024 + d0;
  bf16x8 u0 = *(const bf16x8*)up;
  bf16x8 u1 = *(const bf16x8*)(up + 8);
  bf16x8 v0 = *(const bf16x8*)vp;
  bf16x8 v1 = *(const bf16x8*)(vp + 8);
  float f[16];
#pragma unroll
  for (int j = 0; j < 8; ++j) {
    f[j] = (float)u0[j] + (float)v0[j] + mb0[d0 + j];
    f[8 + j] = (float)u1[j] + (float)v1[j] + mb0[d0 + 8 + j];
  }
  float s1 = 0.f, s2 = 0.f;
#pragma unroll
  for (int j = 0; j < 16; ++j) { s1 += f[j]; s2 += f[j] * f[j]; }
#pragma unroll
  for (int off = 32; off > 0; off >>= 1) {
    s1 += __shfl_xor(s1, off);
    s2 += __shfl_xor(s2, off);
  }
  const float invD = 1.0f / 1024.0f;
  float mean = s1 * invD;
  float var = s2 * invD - mean * mean;
  float inv = rsqrtf(var + LN_EPS);
  bf16_t o0[8], o1[8];
#pragma unroll
  for (int j = 0; j < 8; ++j) {
    o0[j] = (bf16_t)fmaxf((f[j] - mean) * inv * g[d0 + j] + b[d0 + j], 0.f);
    o1[j] = (bf16_t)fmaxf((f[8 + j] - mean) * inv * g[d0 + 8 + j] + b[d0 + 8 + j], 0.f);
  }
  bf16_t* zp = z0 + (size_t)row * 1024 + d0;
  *(bf16x8*)zp = *(bf16x8*)o0;
  *(bf16x8*)(zp + 8) = *(bf16x8*)o1;
}

// wave-per-row: out[row] = dot(relu(LN(z1[row])), mw2) + mb2, D=512
__global__ __launch_bounds__(256) void k_ln_dot(
    const bf16_t* __restrict__ z1, const float* __restrict__ g,
    const float* __restrict__ b, const float* __restrict__ mw2,
    const float* __restrict__ mb2, float* __restrict__ out, int rows) {
  int w = threadIdx.x >> 6, lane = threadIdx.x & 63;
  int row = blockIdx.x * 4 + w;
  if (row >= rows) return;
  int d0 = lane << 3;
  bf16x8 v = *(const bf16x8*)(z1 + (size_t)row * 512 + d0);
  float f[8];
#pragma unroll
  for (int j = 0; j < 8; ++j) f[j] = (float)v[j];
  float s1 = 0.f, s2 = 0.f;
#pragma unroll
  for (int j = 0; j < 8; ++j) { s1 += f[j]; s2 += f[j] * f[j]; }
#pragma unroll
  for (int off = 32; off > 0; off >>= 1) {
    s1 += __shfl_xor(s1, off);
    s2 += __shfl_xor(s2, off);
  }
  const float invD = 1.0f / 512.0f;
  float mean = s1 * invD;
  float var = s2 * invD - mean * mean;
  float inv = rsqrtf(var + LN_EPS);
  float acc = 0.f;
#pragma unroll
  for (int j = 0; j < 8; ++j) {
    float y = fmaxf((f[j] - mean) * inv * g[d0 + j] + b[d0 + j], 0.f);
    acc += y * mw2[d0 + j];
  }
#pragma unroll
  for (int off = 32; off > 0; off >>= 1) acc += __shfl_xor(acc, off);
  if (lane == 0) out[row] = acc + mb2[0];
}

// ---------------- streaming GEMM, BK=64, single-buffered, XCD-co-located --------
// C[M x N] = bf16(A @ Bt^T + bias). Grid: x = row-blocks (padded to x8), y = cols.
// LDS row = 128 B (8 x 16B slots). Slot s of row r holds global k-chunk (s+r)&7
// (per-lane global rotate; LDS writes stay lane-contiguous for global_load_lds).
// Fragment read of chunk c hits slot (c-r)&7 -> bank group (c-r)&7, 2-way = free.
template <int BMt, int BNt>
__global__ __launch_bounds__(256) void k_gemm(
    const bf16_t* __restrict__ A, const bf16_t* __restrict__ Bt,
    const float* __restrict__ bias, bf16_t* __restrict__ C,
    int M, int N, int K) {
  constexpr int RI = BMt / 32, CJ = BNt / 32;
  constexpr int HA = BMt / 32, HB = BNt / 32;  // staging steps (256 thr, 8 chunks/row)
  __shared__ __align__(16) bf16_t sA[BMt * BK];
  __shared__ __align__(16) bf16_t sB[BNt * BK];

  int tid = threadIdx.x;
  int row0 = blockIdx.x * BMt, col0 = blockIdx.y * BNt;
  if (row0 >= M) return;  // padded row-blocks
  int lane = tid & 63, w = tid >> 6;
  int quad = lane >> 4, l15 = lane & 15;
  int wr = (w >> 1) * (BMt / 2), wc = (w & 1) * (BNt / 2);

  int rbase = tid >> 3;                       // row within 32-row staging step
  int gk = ((tid & 7) + rbase) & 7;           // rotated global k-chunk (h-invariant)
  int ksegg = gk << 3;

  const bf16_t* pa[HA];
  const bf16_t* pb[HB];
#pragma unroll
  for (int h = 0; h < HA; ++h) {
    int g0 = row0 + rbase + h * 32;
    if (g0 >= M) g0 = M - 1;  // clamp; never stored
    pa[h] = A + (size_t)g0 * K;
  }
#pragma unroll
  for (int h = 0; h < HB; ++h)
    pb[h] = Bt + (size_t)(col0 + rbase + h * 32) * K;

  int ldsb = (tid & ~63) * 8;  // wave-uniform LDS element base; +2048/h-step

  f32x4 acc[RI][CJ] = {};

  for (int k0 = 0; k0 < K; k0 += BK) {
    int kk = k0 + ksegg;
#pragma unroll
    for (int h = 0; h < HA; ++h) gload_lds16(pa[h] + kk, sA + ldsb + h * 2048);
#pragma unroll
    for (int h = 0; h < HB; ++h) gload_lds16(pb[h] + kk, sB + ldsb + h * 2048);
    __syncthreads();  // drains lds-DMA (vmcnt) before fragment reads

#pragma unroll
    for (int w2 = 0; w2 < 2; ++w2) {
      bf16x8 af[RI], bfr[CJ];
#pragma unroll
      for (int i = 0; i < RI; ++i) {
        int rr = wr + (i << 4) + l15;
        int slot = ((w2 << 2) + quad - rr) & 7;
        af[i] = *(const bf16x8*)&sA[rr * BK + (slot << 3)];
      }
#pragma unroll
      for (int j = 0; j < CJ; ++j) {
        int rr = wc + (j << 4) + l15;
        int slot = ((w2 << 2) + quad - rr) & 7;
        bfr[j] = *(const bf16x8*)&sB[rr * BK + (slot << 3)];
      }
#pragma unroll
      for (int i = 0; i < RI; ++i)
#pragma unroll
        for (int j = 0; j < CJ; ++j)
          acc[i][j] = __builtin_amdgcn_mfma_f32_16x16x32_bf16(af[i], bfr[j], acc[i][j], 0, 0, 0);
    }
    __syncthreads();  // reads done before next stage overwrites
  }

  // epilogue: C/D layout col=lane&15, row=quad*4+reg (verified m89/m91)
#pragma unroll
  for (int i = 0; i < RI; ++i) {
    int r0e = row0 + wr + (i << 4) + (quad << 2);
#pragma unroll
    for (int j = 0; j < CJ; ++j) {
      int gc = col0 + wc + (j << 4) + l15;
      float bb = bias ? bias[gc] : 0.0f;
#pragma unroll
      for (int r2 = 0; r2 < 4; ++r2) {
        int gr = r0e + r2;
        if (gr < M) C[(size_t)gr * N + gc] = (bf16_t)(acc[i][j][r2] + bb);
      }
    }
  }
}

// ---------------- host launch ----------------

static inline int pad8(int x) { return (x + 7) & ~7; }

extern "C" void kernel_launch(void* const* d_in, const int* in_sizes, int n_in,
                              void* d_out, int out_size, void* d_ws, size_t ws_size,
                              hipStream_t stream) {
  const float* x = (const float*)d_in[0];
  const int* ei = (const int*)d_in[1];
  const float* w0 = (const float*)d_in[2];
  const float* b0 = (const float*)d_in[3];
  const float* wsL = (const float*)d_in[4];
  const float* bsL = (const float*)d_in[5];
  const float* ln_g = (const float*)d_in[6];
  const float* ln_b = (const float*)d_in[7];
  const float* mw0 = (const float*)d_in[8];
  const float* mb0 = (const float*)d_in[9];
  const float* mg0 = (const float*)d_in[10];
  const float* mbt0 = (const float*)d_in[11];
  const float* mw1 = (const float*)d_in[12];
  const float* mb1 = (const float*)d_in[13];
  const float* mg1 = (const float*)d_in[14];
  const float* mbt1 = (const float*)d_in[15];
  const float* mw2 = (const float*)d_in[16];
  const float* mb2 = (const float*)d_in[17];
  float* out = (float*)d_out;

  char* p = (char*)d_ws;
  auto alloc = [&](size_t bytes) -> void* {
    void* r = (void*)p;
    p += (bytes + 255) & ~(size_t)255;
    return r;
  };
  float* dis = (float*)alloc((size_t)N_NODES * 4);
  int* cnt = (int*)alloc((size_t)N_NODES * 4);
  int* cursor = (int*)alloc((size_t)N_NODES * 4);
  int* rowptr = (int*)alloc((size_t)(N_NODES + 1) * 4);
  int* esrc = (int*)alloc((size_t)N_EDGES * 4);
  float* ew = (float*)alloc((size_t)N_EDGES * 4);
  bf16_t* xb = (bf16_t*)alloc((size_t)N_NODES * IN_DIM * 2);
  bf16_t* hb0 = (bf16_t*)alloc((size_t)N_NODES * HID * 2);
  bf16_t* hb1 = (bf16_t*)alloc((size_t)N_NODES * HID * 2);
  bf16_t* w0t = (bf16_t*)alloc((size_t)HID * IN_DIM * 2);
  bf16_t* wst = (bf16_t*)alloc((size_t)3 * HID * HID * 2);
  bf16_t* mw0t = (bf16_t*)alloc((size_t)2048 * 512 * 2);  // [W0_top | W0_bot] as Bt
  bf16_t* mw1t = (bf16_t*)alloc((size_t)512 * 1024 * 2);
  bf16_t* UV = (bf16_t*)alloc((size_t)N_NODES * 2048 * 2);  // 41 MB
  size_t fixed = (size_t)(p - (char*)d_ws);

  // overlap pool: GCN-phase T (10.24 MB) vs MLP z0 (2048 B/edge) + z1 (1024 B/edge)
  int CE = 16000;
  const int ce_opts[3] = {80000, 32000, 16000};  // multiples of 128, divide 160000
  for (int i = 0; i < 3; ++i) {
    size_t pool_need = (size_t)ce_opts[i] * 3072;
    size_t tneed = (size_t)N_NODES * HID * 2;
    if (pool_need < tneed) pool_need = tneed;
    if (fixed + pool_need + 4096 <= ws_size) { CE = ce_opts[i]; break; }
  }
  char* pool = p;
  bf16_t* T = (bf16_t*)pool;
  bf16_t* z0 = (bf16_t*)pool;  // aliases T; GCN fully precedes MLP (same stream)
  bf16_t* z1 = (bf16_t*)(pool + (size_t)CE * 2048);

  k_cast<<<(N_NODES * IN_DIM + 255) / 256, 256, 0, stream>>>(x, xb, N_NODES * IN_DIM);
  { dim3 g(HID / 32, IN_DIM / 32);
    k_tpose<<<g, 256, 0, stream>>>(w0, w0t, IN_DIM, HID); }
  for (int i = 0; i < 3; ++i) {
    dim3 g(HID / 32, HID / 32);
    k_tpose<<<g, 256, 0, stream>>>(wsL + (size_t)i * HID * HID,
                                   wst + (size_t)i * HID * HID, HID, HID);
  }
  { dim3 g(1024 / 32, 512 / 32);
    k_tpose<<<g, 256, 0, stream>>>(mw0, mw0t, 512, 1024);                       // top
    k_tpose<<<g, 256, 0, stream>>>(mw0 + (size_t)512 * 1024,
                                   mw0t + (size_t)1024 * 512, 512, 1024); }     // bot
  { dim3 g(512 / 32, 1024 / 32);
    k_tpose<<<g, 256, 0, stream>>>(mw1, mw1t, 1024, 512); }

  // CSR + degree norm (deg == cnt + 1, so one count serves both)
  k_zero2<<<(N_NODES + 255) / 256, 256, 0, stream>>>(cnt, cursor);
  k_cnt<<<(N_EDGES + 255) / 256, 256, 0, stream>>>(ei + N_EDGES, cnt);
  k_dis<<<(N_NODES + 255) / 256, 256, 0, stream>>>(cnt, dis);
  k_scan<<<1, 256, 0, stream>>>(cnt, rowptr);
  k_fill<<<(N_EDGES + 255) / 256, 256, 0, stream>>>(ei, dis, rowptr, cursor, esrc, ew);

  // ---- 4 GCN layers ----
  int nrb64 = pad8((N_NODES + 63) / 64);  // 157 -> 160
  bf16_t* hbufs[2] = {hb0, hb1};
  for (int L = 0; L < 4; ++L) {
    const bf16_t* Ain = (L == 0) ? xb : hbufs[(L + 1) & 1];
    int K = (L == 0) ? IN_DIM : HID;
    const bf16_t* Bt = (L == 0) ? w0t : wst + (size_t)(L - 1) * HID * HID;
    dim3 grid(nrb64, HID / 128);
    k_gemm<64, 128><<<grid, 256, 0, stream>>>(Ain, Bt, nullptr, T, N_NODES, HID, K);
    const float* bias = (L == 0) ? b0 : bsL + (size_t)(L - 1) * HID;
    k_agg_ln<<<(N_NODES + 3) / 4, 256, 0, stream>>>(
        T, rowptr, esrc, ew, dis, bias, ln_g + (size_t)L * HID,
        ln_b + (size_t)L * HID, hbufs[L & 1]);
  }
  bf16_t* hfin = hbufs[1];

  // ---- node-level UV = hfin @ [W0_top | W0_bot]  (10000 x 2048, K=512) ----
  { dim3 g(nrb64, 2048 / 128);
    k_gemm<64, 128><<<g, 256, 0, stream>>>(hfin, mw0t, nullptr, UV, N_NODES, 2048, 512); }

  // ---- edge MLP, chunked ----
  int nchunks = N_EDGES / CE;
  for (int c = 0; c < nchunks; ++c) {
    int e0 = c * CE;
    k_uv_ln<<<CE / 4, 256, 0, stream>>>(UV, ei + e0, ei + N_EDGES + e0, mb0, mg0,
                                        mbt0, z0, CE);
    dim3 g2(pad8(CE / 128), HID / 128);
    k_gemm<128, 128><<<g2, 256, 0, stream>>>(z0, mw1t, mb1, z1, CE, HID, 1024);
    k_ln_dot<<<CE / 4, 256, 0, stream>>>(z1, mg1, mbt1, mw2, mb2, out + e0, CE);
  }
  (void)in_sizes; (void)n_in; (void)out_size;
}

// Round 12
// 812.277 us; speedup vs baseline: 1.3703x; 1.1143x over previous
//
#include <hip/hip_runtime.h>
#include <hip/hip_bf16.h>
#include <stdint.h>

typedef __bf16 bf16_t;
typedef bf16_t bf16x8 __attribute__((ext_vector_type(8)));
typedef float f32x4 __attribute__((ext_vector_type(4)));

#define N_NODES 10000
#define N_EDGES 160000
#define IN_DIM 128
#define HID 512
#define LN_EPS 1e-5f
#define BK 64  // 128 B per tile row: 8 x 16B chunks

#define AS1 __attribute__((address_space(1)))
#define AS3 __attribute__((address_space(3)))

static __device__ __forceinline__ void gload_lds16(const void* g, void* l) {
  __builtin_amdgcn_global_load_lds((const AS1 void*)g, (AS3 void*)l, 16, 0, 0);
}

// ---------------- small utility kernels ----------------

__global__ void k_cast(const float* __restrict__ s, bf16_t* __restrict__ d, int n) {
  int i = blockIdx.x * 256 + threadIdx.x;
  if (i < n) d[i] = (bf16_t)s[i];
}

// LDS-tiled transpose+cast: dst[N][K] = bf16(src[K][N]); grid (N/32, K/32), 256 thr
__global__ __launch_bounds__(256) void k_tpose(const float* __restrict__ src,
                                               bf16_t* __restrict__ dst, int K, int N) {
  __shared__ float t[32][33];
  int cx = threadIdx.x & 31, ry = threadIdx.x >> 5;  // 0..31, 0..7
  int n0 = blockIdx.x * 32, k0 = blockIdx.y * 32;
#pragma unroll
  for (int i = 0; i < 32; i += 8)
    t[ry + i][cx] = src[(size_t)(k0 + ry + i) * N + n0 + cx];
  __syncthreads();
#pragma unroll
  for (int i = 0; i < 32; i += 8)
    dst[(size_t)(n0 + ry + i) * K + k0 + cx] = (bf16_t)t[cx][ry + i];
}

// ---------------- CSR build (edges keyed by target) + degree norm ----------------

__global__ void k_zero2(int* a, int* b) {
  int i = blockIdx.x * 256 + threadIdx.x;
  if (i < N_NODES) { a[i] = 0; b[i] = 0; }
}
__global__ void k_cnt(const int* __restrict__ key, int* cnt) {
  int e = blockIdx.x * 256 + threadIdx.x;
  if (e < N_EDGES) atomicAdd(&cnt[key[e]], 1);
}
// dis = rsqrt(deg), deg = in-degree + 1 self-loop = cnt + 1
__global__ void k_dis(const int* __restrict__ cnt, float* __restrict__ dis) {
  int i = blockIdx.x * 256 + threadIdx.x;
  if (i < N_NODES) dis[i] = rsqrtf(1.0f + (float)cnt[i]);
}
// single-block exclusive scan: rowptr[0..N_NODES]
__global__ __launch_bounds__(256) void k_scan(const int* __restrict__ cnt,
                                              int* __restrict__ rowptr) {
  __shared__ int part[256];
  __shared__ int pref[257];
  int tid = threadIdx.x;
  const int CH = 40;  // 256*40 >= 10001
  int s = 0;
  for (int i = 0; i < CH; ++i) {
    int idx = tid * CH + i;
    if (idx < N_NODES) s += cnt[idx];
  }
  part[tid] = s;
  __syncthreads();
  if (tid == 0) {
    int a = 0;
    for (int i = 0; i < 256; ++i) { pref[i] = a; a += part[i]; }
    pref[256] = a;
  }
  __syncthreads();
  int a = pref[tid];
  for (int i = 0; i < CH; ++i) {
    int idx = tid * CH + i;
    if (idx < N_NODES) {
      rowptr[idx] = a;
      a += cnt[idx];
    } else if (idx == N_NODES) {
      rowptr[idx] = a;
    }
  }
}
// target-CSR fill (aggregation): src + weight per slot
__global__ void k_fill(const int* __restrict__ ei, const float* __restrict__ dis,
                       const int* __restrict__ rowptr, int* __restrict__ cursor,
                       int* __restrict__ esrc, float* __restrict__ ew) {
  int e = blockIdx.x * 256 + threadIdx.x;
  if (e >= N_EDGES) return;
  int s = ei[e];
  int t = ei[N_EDGES + e];
  int pos = atomicAdd(&cursor[t], 1);
  int o = rowptr[t] + pos;
  esrc[o] = s;
  ew[o] = dis[s] * dis[t];
}

// ---------------- fused aggregation + ReLU + LayerNorm (T in bf16) ----------------
__global__ __launch_bounds__(256) void k_agg_ln(
    const bf16_t* __restrict__ T, const int* __restrict__ rowptr,
    const int* __restrict__ esrc, const float* __restrict__ ew,
    const float* __restrict__ dis, const float* __restrict__ bias,
    const float* __restrict__ g, const float* __restrict__ b,
    bf16_t* __restrict__ out) {
  int w = threadIdx.x >> 6, lane = threadIdx.x & 63;
  int node = blockIdx.x * 4 + w;
  if (node >= N_NODES) return;
  int d0 = lane << 3;  // 8 dims per lane
  float dw = dis[node];
  dw *= dw;
  float a[8];
  {
    bf16x8 tn = *(const bf16x8*)(T + (size_t)node * HID + d0);
    const f32x4* bi = (const f32x4*)(bias + d0);
    f32x4 bv0 = bi[0], bv1 = bi[1];
#pragma unroll
    for (int j = 0; j < 4; ++j) a[j] = dw * (float)tn[j] + bv0[j];
#pragma unroll
    for (int j = 0; j < 4; ++j) a[4 + j] = dw * (float)tn[4 + j] + bv1[j];
  }
  int e = rowptr[node], e1 = rowptr[node + 1];
  // 4-way unrolled gather: more loads in flight per wave (latency-bound loop)
  for (; e + 3 < e1; e += 4) {
    int s0 = esrc[e], s1i = esrc[e + 1], s2i = esrc[e + 2], s3i = esrc[e + 3];
    float w0 = ew[e], w1 = ew[e + 1], w2 = ew[e + 2], w3 = ew[e + 3];
    bf16x8 t0 = *(const bf16x8*)(T + (size_t)s0 * HID + d0);
    bf16x8 t1 = *(const bf16x8*)(T + (size_t)s1i * HID + d0);
    bf16x8 t2 = *(const bf16x8*)(T + (size_t)s2i * HID + d0);
    bf16x8 t3 = *(const bf16x8*)(T + (size_t)s3i * HID + d0);
#pragma unroll
    for (int j = 0; j < 8; ++j)
      a[j] += w0 * (float)t0[j] + w1 * (float)t1[j] + w2 * (float)t2[j] + w3 * (float)t3[j];
  }
  for (; e < e1; ++e) {
    int s0 = esrc[e];
    float w0 = ew[e];
    bf16x8 t0 = *(const bf16x8*)(T + (size_t)s0 * HID + d0);
#pragma unroll
    for (int j = 0; j < 8; ++j) a[j] += w0 * (float)t0[j];
  }
  float s1 = 0.f, s2 = 0.f;
#pragma unroll
  for (int j = 0; j < 8; ++j) {
    a[j] = fmaxf(a[j], 0.f);
    s1 += a[j];
    s2 += a[j] * a[j];
  }
#pragma unroll
  for (int off = 32; off > 0; off >>= 1) {
    s1 += __shfl_xor(s1, off);
    s2 += __shfl_xor(s2, off);
  }
  const float invD = 1.0f / (float)HID;
  float mean = s1 * invD;
  float var = s2 * invD - mean * mean;
  float inv = rsqrtf(var + LN_EPS);
  bf16_t ob[8];
#pragma unroll
  for (int j = 0; j < 8; ++j) {
    int d = d0 + j;
    ob[j] = (bf16_t)((a[j] - mean) * inv * g[d] + b[d]);
  }
  *(bf16x8*)(out + (size_t)node * HID + d0) = *(bf16x8*)ob;
}

// ---------------- per-edge: z0 = relu(LN(UV[src][0:1024] + UV[dst][1024:2048] + mb0))
// 2 edges per wave: independent gather+LN chains interleave (latency hiding).
__global__ __launch_bounds__(256) void k_uv_ln(
    const bf16_t* __restrict__ UV, const int* __restrict__ srcI,
    const int* __restrict__ dstI, const float* __restrict__ mb0,
    const float* __restrict__ g, const float* __restrict__ b,
    bf16_t* __restrict__ z0, int rows) {
  int w = threadIdx.x >> 6, lane = threadIdx.x & 63;
  int row0 = blockIdx.x * 8 + w * 2;  // rows always even (multiples of 128/16000)
  if (row0 >= rows) return;
  int d0 = lane << 4;  // 16 dims per lane
  int sA = srcI[row0], tA = dstI[row0];
  int sB = srcI[row0 + 1], tB = dstI[row0 + 1];
  const bf16_t* upA = UV + (size_t)sA * 2048 + d0;
  const bf16_t* vpA = UV + (size_t)tA * 2048 + 1024 + d0;
  const bf16_t* upB = UV + (size_t)sB * 2048 + d0;
  const bf16_t* vpB = UV + (size_t)tB * 2048 + 1024 + d0;
  bf16x8 uA0 = *(const bf16x8*)upA, uA1 = *(const bf16x8*)(upA + 8);
  bf16x8 vA0 = *(const bf16x8*)vpA, vA1 = *(const bf16x8*)(vpA + 8);
  bf16x8 uB0 = *(const bf16x8*)upB, uB1 = *(const bf16x8*)(upB + 8);
  bf16x8 vB0 = *(const bf16x8*)vpB, vB1 = *(const bf16x8*)(vpB + 8);
  float fA[16], fB[16];
#pragma unroll
  for (int j = 0; j < 8; ++j) {
    float m0 = mb0[d0 + j], m1 = mb0[d0 + 8 + j];
    fA[j] = (float)uA0[j] + (float)vA0[j] + m0;
    fA[8 + j] = (float)uA1[j] + (float)vA1[j] + m1;
    fB[j] = (float)uB0[j] + (float)vB0[j] + m0;
    fB[8 + j] = (float)uB1[j] + (float)vB1[j] + m1;
  }
  float s1A = 0.f, s2A = 0.f, s1B = 0.f, s2B = 0.f;
#pragma unroll
  for (int j = 0; j < 16; ++j) {
    s1A += fA[j]; s2A += fA[j] * fA[j];
    s1B += fB[j]; s2B += fB[j] * fB[j];
  }
#pragma unroll
  for (int off = 32; off > 0; off >>= 1) {
    s1A += __shfl_xor(s1A, off); s2A += __shfl_xor(s2A, off);
    s1B += __shfl_xor(s1B, off); s2B += __shfl_xor(s2B, off);
  }
  const float invD = 1.0f / 1024.0f;
  float meanA = s1A * invD, meanB = s1B * invD;
  float invA = rsqrtf(s2A * invD - meanA * meanA + LN_EPS);
  float invB = rsqrtf(s2B * invD - meanB * meanB + LN_EPS);
  bf16_t oA0[8], oA1[8], oB0[8], oB1[8];
#pragma unroll
  for (int j = 0; j < 8; ++j) {
    float g0 = g[d0 + j], g1 = g[d0 + 8 + j];
    float b0v = b[d0 + j], b1v = b[d0 + 8 + j];
    oA0[j] = (bf16_t)fmaxf((fA[j] - meanA) * invA * g0 + b0v, 0.f);
    oA1[j] = (bf16_t)fmaxf((fA[8 + j] - meanA) * invA * g1 + b1v, 0.f);
    oB0[j] = (bf16_t)fmaxf((fB[j] - meanB) * invB * g0 + b0v, 0.f);
    oB1[j] = (bf16_t)fmaxf((fB[8 + j] - meanB) * invB * g1 + b1v, 0.f);
  }
  bf16_t* zpA = z0 + (size_t)row0 * 1024 + d0;
  bf16_t* zpB = zpA + 1024;
  *(bf16x8*)zpA = *(bf16x8*)oA0;
  *(bf16x8*)(zpA + 8) = *(bf16x8*)oA1;
  *(bf16x8*)zpB = *(bf16x8*)oB0;
  *(bf16x8*)(zpB + 8) = *(bf16x8*)oB1;
}

// 2 rows per wave: out[row] = dot(relu(LN(z1[row])), mw2) + mb2, D=512
__global__ __launch_bounds__(256) void k_ln_dot(
    const bf16_t* __restrict__ z1, const float* __restrict__ g,
    const float* __restrict__ b, const float* __restrict__ mw2,
    const float* __restrict__ mb2, float* __restrict__ out, int rows) {
  int w = threadIdx.x >> 6, lane = threadIdx.x & 63;
  int row0 = blockIdx.x * 8 + w * 2;
  if (row0 >= rows) return;
  int d0 = lane << 3;
  bf16x8 vA = *(const bf16x8*)(z1 + (size_t)row0 * 512 + d0);
  bf16x8 vB = *(const bf16x8*)(z1 + (size_t)(row0 + 1) * 512 + d0);
  float fA[8], fB[8];
#pragma unroll
  for (int j = 0; j < 8; ++j) { fA[j] = (float)vA[j]; fB[j] = (float)vB[j]; }
  float s1A = 0.f, s2A = 0.f, s1B = 0.f, s2B = 0.f;
#pragma unroll
  for (int j = 0; j < 8; ++j) {
    s1A += fA[j]; s2A += fA[j] * fA[j];
    s1B += fB[j]; s2B += fB[j] * fB[j];
  }
#pragma unroll
  for (int off = 32; off > 0; off >>= 1) {
    s1A += __shfl_xor(s1A, off); s2A += __shfl_xor(s2A, off);
    s1B += __shfl_xor(s1B, off); s2B += __shfl_xor(s2B, off);
  }
  const float invD = 1.0f / 512.0f;
  float meanA = s1A * invD, meanB = s1B * invD;
  float invA = rsqrtf(s2A * invD - meanA * meanA + LN_EPS);
  float invB = rsqrtf(s2B * invD - meanB * meanB + LN_EPS);
  float accA = 0.f, accB = 0.f;
#pragma unroll
  for (int j = 0; j < 8; ++j) {
    float gv = g[d0 + j], bv = b[d0 + j], wv = mw2[d0 + j];
    accA += fmaxf((fA[j] - meanA) * invA * gv + bv, 0.f) * wv;
    accB += fmaxf((fB[j] - meanB) * invB * gv + bv, 0.f) * wv;
  }
#pragma unroll
  for (int off = 32; off > 0; off >>= 1) {
    accA += __shfl_xor(accA, off);
    accB += __shfl_xor(accB, off);
  }
  if (lane == 0) {
    out[row0] = accA + mb2[0];
    out[row0 + 1] = accB + mb2[0];
  }
}

// ---------------- streaming GEMM, BK=64, single-buffered, XCD-co-located --------
// C[M x N] = bf16(A @ Bt^T + bias). Grid: x = row-blocks (padded to x8), y = cols.
// LDS row = 128 B (8 x 16B slots). Slot s of row r holds global k-chunk (s+r)&7;
// fragment read of chunk c hits slot (c-r)&7 -> 2-way bank aliasing = free.
template <int BMt, int BNt>
__global__ __launch_bounds__(256) void k_gemm(
    const bf16_t* __restrict__ A, const bf16_t* __restrict__ Bt,
    const float* __restrict__ bias, bf16_t* __restrict__ C,
    int M, int N, int K) {
  constexpr int RI = BMt / 32, CJ = BNt / 32;
  constexpr int HA = BMt / 32, HB = BNt / 32;
  __shared__ __align__(16) bf16_t sA[BMt * BK];
  __shared__ __align__(16) bf16_t sB[BNt * BK];

  int tid = threadIdx.x;
  int row0 = blockIdx.x * BMt, col0 = blockIdx.y * BNt;
  if (row0 >= M) return;  // padded row-blocks
  int lane = tid & 63, w = tid >> 6;
  int quad = lane >> 4, l15 = lane & 15;
  int wr = (w >> 1) * (BMt / 2), wc = (w & 1) * (BNt / 2);

  int rbase = tid >> 3;                       // row within 32-row staging step
  int gk = ((tid & 7) + rbase) & 7;           // rotated global k-chunk
  int ksegg = gk << 3;

  const bf16_t* pa[HA];
  const bf16_t* pb[HB];
#pragma unroll
  for (int h = 0; h < HA; ++h) {
    int g0 = row0 + rbase + h * 32;
    if (g0 >= M) g0 = M - 1;  // clamp; never stored
    pa[h] = A + (size_t)g0 * K;
  }
#pragma unroll
  for (int h = 0; h < HB; ++h)
    pb[h] = Bt + (size_t)(col0 + rbase + h * 32) * K;

  int ldsb = (tid & ~63) * 8;

  f32x4 acc[RI][CJ] = {};

  for (int k0 = 0; k0 < K; k0 += BK) {
    int kk = k0 + ksegg;
#pragma unroll
    for (int h = 0; h < HA; ++h) gload_lds16(pa[h] + kk, sA + ldsb + h * 2048);
#pragma unroll
    for (int h = 0; h < HB; ++h) gload_lds16(pb[h] + kk, sB + ldsb + h * 2048);
    __syncthreads();

#pragma unroll
    for (int w2 = 0; w2 < 2; ++w2) {
      bf16x8 af[RI], bfr[CJ];
#pragma unroll
      for (int i = 0; i < RI; ++i) {
        int rr = wr + (i << 4) + l15;
        int slot = ((w2 << 2) + quad - rr) & 7;
        af[i] = *(const bf16x8*)&sA[rr * BK + (slot << 3)];
      }
#pragma unroll
      for (int j = 0; j < CJ; ++j) {
        int rr = wc + (j << 4) + l15;
        int slot = ((w2 << 2) + quad - rr) & 7;
        bfr[j] = *(const bf16x8*)&sB[rr * BK + (slot << 3)];
      }
#pragma unroll
      for (int i = 0; i < RI; ++i)
#pragma unroll
        for (int j = 0; j < CJ; ++j)
          acc[i][j] = __builtin_amdgcn_mfma_f32_16x16x32_bf16(af[i], bfr[j], acc[i][j], 0, 0, 0);
    }
    __syncthreads();
  }

  // epilogue: C/D layout col=lane&15, row=quad*4+reg (verified m89/m91)
#pragma unroll
  for (int i = 0; i < RI; ++i) {
    int r0e = row0 + wr + (i << 4) + (quad << 2);
#pragma unroll
    for (int j = 0; j < CJ; ++j) {
      int gc = col0 + wc + (j << 4) + l15;
      float bb = bias ? bias[gc] : 0.0f;
#pragma unroll
      for (int r2 = 0; r2 < 4; ++r2) {
        int gr = r0e + r2;
        if (gr < M) C[(size_t)gr * N + gc] = (bf16_t)(acc[i][j][r2] + bb);
      }
    }
  }
}

// ---------------- host launch ----------------

static inline int pad8(int x) { return (x + 7) & ~7; }

extern "C" void kernel_launch(void* const* d_in, const int* in_sizes, int n_in,
                              void* d_out, int out_size, void* d_ws, size_t ws_size,
                              hipStream_t stream) {
  const float* x = (const float*)d_in[0];
  const int* ei = (const int*)d_in[1];
  const float* w0 = (const float*)d_in[2];
  const float* b0 = (const float*)d_in[3];
  const float* wsL = (const float*)d_in[4];
  const float* bsL = (const float*)d_in[5];
  const float* ln_g = (const float*)d_in[6];
  const float* ln_b = (const float*)d_in[7];
  const float* mw0 = (const float*)d_in[8];
  const float* mb0 = (const float*)d_in[9];
  const float* mg0 = (const float*)d_in[10];
  const float* mbt0 = (const float*)d_in[11];
  const float* mw1 = (const float*)d_in[12];
  const float* mb1 = (const float*)d_in[13];
  const float* mg1 = (const float*)d_in[14];
  const float* mbt1 = (const float*)d_in[15];
  const float* mw2 = (const float*)d_in[16];
  const float* mb2 = (const float*)d_in[17];
  float* out = (float*)d_out;

  char* p = (char*)d_ws;
  auto alloc = [&](size_t bytes) -> void* {
    void* r = (void*)p;
    p += (bytes + 255) & ~(size_t)255;
    return r;
  };
  float* dis = (float*)alloc((size_t)N_NODES * 4);
  int* cnt = (int*)alloc((size_t)N_NODES * 4);
  int* cursor = (int*)alloc((size_t)N_NODES * 4);
  int* rowptr = (int*)alloc((size_t)(N_NODES + 1) * 4);
  int* esrc = (int*)alloc((size_t)N_EDGES * 4);
  float* ew = (float*)alloc((size_t)N_EDGES * 4);
  bf16_t* xb = (bf16_t*)alloc((size_t)N_NODES * IN_DIM * 2);
  bf16_t* hb0 = (bf16_t*)alloc((size_t)N_NODES * HID * 2);
  bf16_t* hb1 = (bf16_t*)alloc((size_t)N_NODES * HID * 2);
  bf16_t* w0t = (bf16_t*)alloc((size_t)HID * IN_DIM * 2);
  bf16_t* wst = (bf16_t*)alloc((size_t)3 * HID * HID * 2);
  bf16_t* mw0t = (bf16_t*)alloc((size_t)2048 * 512 * 2);  // [W0_top | W0_bot] as Bt
  bf16_t* mw1t = (bf16_t*)alloc((size_t)512 * 1024 * 2);
  bf16_t* UV = (bf16_t*)alloc((size_t)N_NODES * 2048 * 2);  // 41 MB
  size_t fixed = (size_t)(p - (char*)d_ws);

  // overlap pool: GCN-phase T (10.24 MB) vs MLP z0 (2048 B/edge) + z1 (1024 B/edge).
  // ws_size is known >= ~235 MB (r8 fit CE=80000 at 2048 B/edge), so 48000 fits.
  // Larger options probed first; last chunk may be ragged (multiple of 128 not req'd
  // for the tail since all kernels take a rows/M argument).
  int CE = 16000;
  const int ce_opts[5] = {70400, 64000, 48000, 32000, 16000};  // multiples of 128
  for (int i = 0; i < 5; ++i) {
    size_t pool_need = (size_t)ce_opts[i] * 3072;
    size_t tneed = (size_t)N_NODES * HID * 2;
    if (pool_need < tneed) pool_need = tneed;
    if (fixed + pool_need + 4096 <= ws_size) { CE = ce_opts[i]; break; }
  }
  char* pool = p;
  bf16_t* T = (bf16_t*)pool;
  bf16_t* z0 = (bf16_t*)pool;  // aliases T; GCN fully precedes MLP (same stream)
  bf16_t* z1 = (bf16_t*)(pool + (size_t)CE * 2048);

  k_cast<<<(N_NODES * IN_DIM + 255) / 256, 256, 0, stream>>>(x, xb, N_NODES * IN_DIM);
  { dim3 g(HID / 32, IN_DIM / 32);
    k_tpose<<<g, 256, 0, stream>>>(w0, w0t, IN_DIM, HID); }
  for (int i = 0; i < 3; ++i) {
    dim3 g(HID / 32, HID / 32);
    k_tpose<<<g, 256, 0, stream>>>(wsL + (size_t)i * HID * HID,
                                   wst + (size_t)i * HID * HID, HID, HID);
  }
  { dim3 g(1024 / 32, 512 / 32);
    k_tpose<<<g, 256, 0, stream>>>(mw0, mw0t, 512, 1024);                       // top
    k_tpose<<<g, 256, 0, stream>>>(mw0 + (size_t)512 * 1024,
                                   mw0t + (size_t)1024 * 512, 512, 1024); }     // bot
  { dim3 g(512 / 32, 1024 / 32);
    k_tpose<<<g, 256, 0, stream>>>(mw1, mw1t, 1024, 512); }

  // CSR + degree norm (deg == cnt + 1, so one count serves both)
  k_zero2<<<(N_NODES + 255) / 256, 256, 0, stream>>>(cnt, cursor);
  k_cnt<<<(N_EDGES + 255) / 256, 256, 0, stream>>>(ei + N_EDGES, cnt);
  k_dis<<<(N_NODES + 255) / 256, 256, 0, stream>>>(cnt, dis);
  k_scan<<<1, 256, 0, stream>>>(cnt, rowptr);
  k_fill<<<(N_EDGES + 255) / 256, 256, 0, stream>>>(ei, dis, rowptr, cursor, esrc, ew);

  // ---- 4 GCN layers ----
  int nrb64 = pad8((N_NODES + 63) / 64);  // 157 -> 160
  bf16_t* hbufs[2] = {hb0, hb1};
  for (int L = 0; L < 4; ++L) {
    const bf16_t* Ain = (L == 0) ? xb : hbufs[(L + 1) & 1];
    int K = (L == 0) ? IN_DIM : HID;
    const bf16_t* Bt = (L == 0) ? w0t : wst + (size_t)(L - 1) * HID * HID;
    dim3 grid(nrb64, HID / 128);
    k_gemm<64, 128><<<grid, 256, 0, stream>>>(Ain, Bt, nullptr, T, N_NODES, HID, K);
    const float* bias = (L == 0) ? b0 : bsL + (size_t)(L - 1) * HID;
    k_agg_ln<<<(N_NODES + 3) / 4, 256, 0, stream>>>(
        T, rowptr, esrc, ew, dis, bias, ln_g + (size_t)L * HID,
        ln_b + (size_t)L * HID, hbufs[L & 1]);
  }
  bf16_t* hfin = hbufs[1];

  // ---- node-level UV = hfin @ [W0_top | W0_bot]  (10000 x 2048, K=512) ----
  { dim3 g(nrb64, 2048 / 128);
    k_gemm<64, 128><<<g, 256, 0, stream>>>(hfin, mw0t, nullptr, UV, N_NODES, 2048, 512); }

  // ---- edge MLP, chunked (ragged last chunk OK) ----
  for (int e0 = 0; e0 < N_EDGES; ) {
    int ce = N_EDGES - e0;
    if (ce > CE) ce = CE;
    k_uv_ln<<<(ce + 7) / 8, 256, 0, stream>>>(UV, ei + e0, ei + N_EDGES + e0, mb0,
                                              mg0, mbt0, z0, ce);
    dim3 g2(pad8((ce + 127) / 128), HID / 128);
    k_gemm<128, 128><<<g2, 256, 0, stream>>>(z0, mw1t, mb1, z1, ce, HID, 1024);
    k_ln_dot<<<(ce + 7) / 8, 256, 0, stream>>>(z1, mg1, mbt1, mw2, mb2, out + e0, ce);
    e0 += ce;
  }
  (void)in_sizes; (void)n_in; (void)out_size;
}

// Round 13
// 775.571 us; speedup vs baseline: 1.4351x; 1.0473x over previous
//
#include <hip/hip_runtime.h>
#include <hip/hip_bf16.h>
#include <stdint.h>

typedef __bf16 bf16_t;
typedef bf16_t bf16x8 __attribute__((ext_vector_type(8)));
typedef float f32x4 __attribute__((ext_vector_type(4)));

#define N_NODES 10000
#define N_EDGES 160000
#define IN_DIM 128
#define HID 512
#define LN_EPS 1e-5f
#define BK 64  // 128 B per tile row: 8 x 16B chunks

#define AS1 __attribute__((address_space(1)))
#define AS3 __attribute__((address_space(3)))

static __device__ __forceinline__ void gload_lds16(const void* g, void* l) {
  __builtin_amdgcn_global_load_lds((const AS1 void*)g, (AS3 void*)l, 16, 0, 0);
}

// ---------------- small utility kernels ----------------

__global__ void k_cast(const float* __restrict__ s, bf16_t* __restrict__ d, int n) {
  int i = blockIdx.x * 256 + threadIdx.x;
  if (i < n) d[i] = (bf16_t)s[i];
}

// LDS-tiled transpose+cast: dst[N][K] = bf16(src[K][N]); grid (N/32, K/32), 256 thr
__global__ __launch_bounds__(256) void k_tpose(const float* __restrict__ src,
                                               bf16_t* __restrict__ dst, int K, int N) {
  __shared__ float t[32][33];
  int cx = threadIdx.x & 31, ry = threadIdx.x >> 5;  // 0..31, 0..7
  int n0 = blockIdx.x * 32, k0 = blockIdx.y * 32;
#pragma unroll
  for (int i = 0; i < 32; i += 8)
    t[ry + i][cx] = src[(size_t)(k0 + ry + i) * N + n0 + cx];
  __syncthreads();
#pragma unroll
  for (int i = 0; i < 32; i += 8)
    dst[(size_t)(n0 + ry + i) * K + k0 + cx] = (bf16_t)t[cx][ry + i];
}

// ---------------- CSR build (edges keyed by target) + degree norm ----------------

__global__ void k_zero2(int* a, int* b) {
  int i = blockIdx.x * 256 + threadIdx.x;
  if (i < N_NODES) { a[i] = 0; b[i] = 0; }
}
__global__ void k_cnt(const int* __restrict__ key, int* cnt) {
  int e = blockIdx.x * 256 + threadIdx.x;
  if (e < N_EDGES) atomicAdd(&cnt[key[e]], 1);
}
// dis = rsqrt(deg), deg = in-degree + 1 self-loop = cnt + 1
__global__ void k_dis(const int* __restrict__ cnt, float* __restrict__ dis) {
  int i = blockIdx.x * 256 + threadIdx.x;
  if (i < N_NODES) dis[i] = rsqrtf(1.0f + (float)cnt[i]);
}
// single-block exclusive scan: rowptr[0..N_NODES]
__global__ __launch_bounds__(256) void k_scan(const int* __restrict__ cnt,
                                              int* __restrict__ rowptr) {
  __shared__ int part[256];
  __shared__ int pref[257];
  int tid = threadIdx.x;
  const int CH = 40;  // 256*40 >= 10001
  int s = 0;
  for (int i = 0; i < CH; ++i) {
    int idx = tid * CH + i;
    if (idx < N_NODES) s += cnt[idx];
  }
  part[tid] = s;
  __syncthreads();
  if (tid == 0) {
    int a = 0;
    for (int i = 0; i < 256; ++i) { pref[i] = a; a += part[i]; }
    pref[256] = a;
  }
  __syncthreads();
  int a = pref[tid];
  for (int i = 0; i < CH; ++i) {
    int idx = tid * CH + i;
    if (idx < N_NODES) {
      rowptr[idx] = a;
      a += cnt[idx];
    } else if (idx == N_NODES) {
      rowptr[idx] = a;
    }
  }
}
// target-CSR fill (aggregation): src + weight per slot
__global__ void k_fill(const int* __restrict__ ei, const float* __restrict__ dis,
                       const int* __restrict__ rowptr, int* __restrict__ cursor,
                       int* __restrict__ esrc, float* __restrict__ ew) {
  int e = blockIdx.x * 256 + threadIdx.x;
  if (e >= N_EDGES) return;
  int s = ei[e];
  int t = ei[N_EDGES + e];
  int pos = atomicAdd(&cursor[t], 1);
  int o = rowptr[t] + pos;
  esrc[o] = s;
  ew[o] = dis[s] * dis[t];
}

// ---------------- fused aggregation + ReLU + LayerNorm (T in bf16) ----------------
__global__ __launch_bounds__(256) void k_agg_ln(
    const bf16_t* __restrict__ T, const int* __restrict__ rowptr,
    const int* __restrict__ esrc, const float* __restrict__ ew,
    const float* __restrict__ dis, const float* __restrict__ bias,
    const float* __restrict__ g, const float* __restrict__ b,
    bf16_t* __restrict__ out) {
  int w = threadIdx.x >> 6, lane = threadIdx.x & 63;
  int node = blockIdx.x * 4 + w;
  if (node >= N_NODES) return;
  int d0 = lane << 3;  // 8 dims per lane
  float dw = dis[node];
  dw *= dw;
  float a[8];
  {
    bf16x8 tn = *(const bf16x8*)(T + (size_t)node * HID + d0);
    const f32x4* bi = (const f32x4*)(bias + d0);
    f32x4 bv0 = bi[0], bv1 = bi[1];
#pragma unroll
    for (int j = 0; j < 4; ++j) a[j] = dw * (float)tn[j] + bv0[j];
#pragma unroll
    for (int j = 0; j < 4; ++j) a[4 + j] = dw * (float)tn[4 + j] + bv1[j];
  }
  int e = rowptr[node], e1 = rowptr[node + 1];
  // 4-way unrolled gather: more loads in flight per wave (latency-bound loop)
  for (; e + 3 < e1; e += 4) {
    int s0 = esrc[e], s1i = esrc[e + 1], s2i = esrc[e + 2], s3i = esrc[e + 3];
    float w0 = ew[e], w1 = ew[e + 1], w2 = ew[e + 2], w3 = ew[e + 3];
    bf16x8 t0 = *(const bf16x8*)(T + (size_t)s0 * HID + d0);
    bf16x8 t1 = *(const bf16x8*)(T + (size_t)s1i * HID + d0);
    bf16x8 t2 = *(const bf16x8*)(T + (size_t)s2i * HID + d0);
    bf16x8 t3 = *(const bf16x8*)(T + (size_t)s3i * HID + d0);
#pragma unroll
    for (int j = 0; j < 8; ++j)
      a[j] += w0 * (float)t0[j] + w1 * (float)t1[j] + w2 * (float)t2[j] + w3 * (float)t3[j];
  }
  for (; e < e1; ++e) {
    int s0 = esrc[e];
    float w0 = ew[e];
    bf16x8 t0 = *(const bf16x8*)(T + (size_t)s0 * HID + d0);
#pragma unroll
    for (int j = 0; j < 8; ++j) a[j] += w0 * (float)t0[j];
  }
  float s1 = 0.f, s2 = 0.f;
#pragma unroll
  for (int j = 0; j < 8; ++j) {
    a[j] = fmaxf(a[j], 0.f);
    s1 += a[j];
    s2 += a[j] * a[j];
  }
#pragma unroll
  for (int off = 32; off > 0; off >>= 1) {
    s1 += __shfl_xor(s1, off);
    s2 += __shfl_xor(s2, off);
  }
  const float invD = 1.0f / (float)HID;
  float mean = s1 * invD;
  float var = s2 * invD - mean * mean;
  float inv = rsqrtf(var + LN_EPS);
  bf16_t ob[8];
#pragma unroll
  for (int j = 0; j < 8; ++j) {
    int d = d0 + j;
    ob[j] = (bf16_t)((a[j] - mean) * inv * g[d] + b[d]);
  }
  *(bf16x8*)(out + (size_t)node * HID + d0) = *(bf16x8*)ob;
}

// ---------------- per-edge: z0 = relu(LN(UV[src][0:1024] + UV[dst][1024:2048] + mb0))
// 2 edges per wave: independent gather+LN chains interleave (latency hiding).
__global__ __launch_bounds__(256) void k_uv_ln(
    const bf16_t* __restrict__ UV, const int* __restrict__ srcI,
    const int* __restrict__ dstI, const float* __restrict__ mb0,
    const float* __restrict__ g, const float* __restrict__ b,
    bf16_t* __restrict__ z0, int rows) {
  int w = threadIdx.x >> 6, lane = threadIdx.x & 63;
  int row0 = blockIdx.x * 8 + w * 2;
  if (row0 >= rows) return;
  int d0 = lane << 4;  // 16 dims per lane
  int sA = srcI[row0], tA = dstI[row0];
  int sB = srcI[row0 + 1], tB = dstI[row0 + 1];
  const bf16_t* upA = UV + (size_t)sA * 2048 + d0;
  const bf16_t* vpA = UV + (size_t)tA * 2048 + 1024 + d0;
  const bf16_t* upB = UV + (size_t)sB * 2048 + d0;
  const bf16_t* vpB = UV + (size_t)tB * 2048 + 1024 + d0;
  bf16x8 uA0 = *(const bf16x8*)upA, uA1 = *(const bf16x8*)(upA + 8);
  bf16x8 vA0 = *(const bf16x8*)vpA, vA1 = *(const bf16x8*)(vpA + 8);
  bf16x8 uB0 = *(const bf16x8*)upB, uB1 = *(const bf16x8*)(upB + 8);
  bf16x8 vB0 = *(const bf16x8*)vpB, vB1 = *(const bf16x8*)(vpB + 8);
  float fA[16], fB[16];
#pragma unroll
  for (int j = 0; j < 8; ++j) {
    float m0 = mb0[d0 + j], m1 = mb0[d0 + 8 + j];
    fA[j] = (float)uA0[j] + (float)vA0[j] + m0;
    fA[8 + j] = (float)uA1[j] + (float)vA1[j] + m1;
    fB[j] = (float)uB0[j] + (float)vB0[j] + m0;
    fB[8 + j] = (float)uB1[j] + (float)vB1[j] + m1;
  }
  float s1A = 0.f, s2A = 0.f, s1B = 0.f, s2B = 0.f;
#pragma unroll
  for (int j = 0; j < 16; ++j) {
    s1A += fA[j]; s2A += fA[j] * fA[j];
    s1B += fB[j]; s2B += fB[j] * fB[j];
  }
#pragma unroll
  for (int off = 32; off > 0; off >>= 1) {
    s1A += __shfl_xor(s1A, off); s2A += __shfl_xor(s2A, off);
    s1B += __shfl_xor(s1B, off); s2B += __shfl_xor(s2B, off);
  }
  const float invD = 1.0f / 1024.0f;
  float meanA = s1A * invD, meanB = s1B * invD;
  float invA = rsqrtf(s2A * invD - meanA * meanA + LN_EPS);
  float invB = rsqrtf(s2B * invD - meanB * meanB + LN_EPS);
  bf16_t oA0[8], oA1[8], oB0[8], oB1[8];
#pragma unroll
  for (int j = 0; j < 8; ++j) {
    float g0 = g[d0 + j], g1 = g[d0 + 8 + j];
    float b0v = b[d0 + j], b1v = b[d0 + 8 + j];
    oA0[j] = (bf16_t)fmaxf((fA[j] - meanA) * invA * g0 + b0v, 0.f);
    oA1[j] = (bf16_t)fmaxf((fA[8 + j] - meanA) * invA * g1 + b1v, 0.f);
    oB0[j] = (bf16_t)fmaxf((fB[j] - meanB) * invB * g0 + b0v, 0.f);
    oB1[j] = (bf16_t)fmaxf((fB[8 + j] - meanB) * invB * g1 + b1v, 0.f);
  }
  bf16_t* zpA = z0 + (size_t)row0 * 1024 + d0;
  bf16_t* zpB = zpA + 1024;
  *(bf16x8*)zpA = *(bf16x8*)oA0;
  *(bf16x8*)(zpA + 8) = *(bf16x8*)oA1;
  *(bf16x8*)zpB = *(bf16x8*)oB0;
  *(bf16x8*)(zpB + 8) = *(bf16x8*)oB1;
}

// 2 rows per wave: out[row] = dot(relu(LN(z1[row])), mw2) + mb2, D=512
__global__ __launch_bounds__(256) void k_ln_dot(
    const bf16_t* __restrict__ z1, const float* __restrict__ g,
    const float* __restrict__ b, const float* __restrict__ mw2,
    const float* __restrict__ mb2, float* __restrict__ out, int rows) {
  int w = threadIdx.x >> 6, lane = threadIdx.x & 63;
  int row0 = blockIdx.x * 8 + w * 2;
  if (row0 >= rows) return;
  int d0 = lane << 3;
  bf16x8 vA = *(const bf16x8*)(z1 + (size_t)row0 * 512 + d0);
  bf16x8 vB = *(const bf16x8*)(z1 + (size_t)(row0 + 1) * 512 + d0);
  float fA[8], fB[8];
#pragma unroll
  for (int j = 0; j < 8; ++j) { fA[j] = (float)vA[j]; fB[j] = (float)vB[j]; }
  float s1A = 0.f, s2A = 0.f, s1B = 0.f, s2B = 0.f;
#pragma unroll
  for (int j = 0; j < 8; ++j) {
    s1A += fA[j]; s2A += fA[j] * fA[j];
    s1B += fB[j]; s2B += fB[j] * fB[j];
  }
#pragma unroll
  for (int off = 32; off > 0; off >>= 1) {
    s1A += __shfl_xor(s1A, off); s2A += __shfl_xor(s2A, off);
    s1B += __shfl_xor(s1B, off); s2B += __shfl_xor(s2B, off);
  }
  const float invD = 1.0f / 512.0f;
  float meanA = s1A * invD, meanB = s1B * invD;
  float invA = rsqrtf(s2A * invD - meanA * meanA + LN_EPS);
  float invB = rsqrtf(s2B * invD - meanB * meanB + LN_EPS);
  float accA = 0.f, accB = 0.f;
#pragma unroll
  for (int j = 0; j < 8; ++j) {
    float gv = g[d0 + j], bv = b[d0 + j], wv = mw2[d0 + j];
    accA += fmaxf((fA[j] - meanA) * invA * gv + bv, 0.f) * wv;
    accB += fmaxf((fB[j] - meanB) * invB * gv + bv, 0.f) * wv;
  }
#pragma unroll
  for (int off = 32; off > 0; off >>= 1) {
    accA += __shfl_xor(accA, off);
    accB += __shfl_xor(accB, off);
  }
  if (lane == 0) {
    out[row0] = accA + mb2[0];
    out[row0 + 1] = accB + mb2[0];
  }
}

// ---------------- streaming GEMM, BK=64, single-buffered ------------------------
// C[M x N] = bf16(A @ Bt^T + bias). 1D grid, temporally-L2-aware XCD decode:
//   id = xcd + 8*(col + ncol*rowgroup), rb = rowgroup*8 + xcd.
// The ncol col-tiles of one row-block land on the SAME XCD at ids differing by 8
// (temporally adjacent) -> A-tile fetched once into that XCD's L2, reused ncol x.
// LDS row = 128 B (8 x 16B slots). Slot s of row r holds global k-chunk (s+r)&7;
// fragment read of chunk c hits slot (c-r)&7 -> 2-way bank aliasing = free.
template <int BMt, int BNt>
__global__ __launch_bounds__(256) void k_gemm(
    const bf16_t* __restrict__ A, const bf16_t* __restrict__ Bt,
    const float* __restrict__ bias, bf16_t* __restrict__ C,
    int M, int N, int K, int ncol) {
  constexpr int RI = BMt / 32, CJ = BNt / 32;
  constexpr int HA = BMt / 32, HB = BNt / 32;
  __shared__ __align__(16) bf16_t sA[BMt * BK];
  __shared__ __align__(16) bf16_t sB[BNt * BK];

  int tid = threadIdx.x;
  int bid = blockIdx.x;
  int xcd = bid & 7;
  int rest = bid >> 3;
  int col = rest % ncol;
  int rb = ((rest / ncol) << 3) + xcd;
  int row0 = rb * BMt, col0 = col * BNt;
  if (row0 >= M) return;  // padded row-blocks
  int lane = tid & 63, w = tid >> 6;
  int quad = lane >> 4, l15 = lane & 15;
  int wr = (w >> 1) * (BMt / 2), wc = (w & 1) * (BNt / 2);

  int rbase = tid >> 3;                       // row within 32-row staging step
  int gk = ((tid & 7) + rbase) & 7;           // rotated global k-chunk
  int ksegg = gk << 3;

  const bf16_t* pa[HA];
  const bf16_t* pb[HB];
#pragma unroll
  for (int h = 0; h < HA; ++h) {
    int g0 = row0 + rbase + h * 32;
    if (g0 >= M) g0 = M - 1;  // clamp; never stored
    pa[h] = A + (size_t)g0 * K;
  }
#pragma unroll
  for (int h = 0; h < HB; ++h)
    pb[h] = Bt + (size_t)(col0 + rbase + h * 32) * K;

  int ldsb = (tid & ~63) * 8;

  f32x4 acc[RI][CJ] = {};

  for (int k0 = 0; k0 < K; k0 += BK) {
    int kk = k0 + ksegg;
#pragma unroll
    for (int h = 0; h < HA; ++h) gload_lds16(pa[h] + kk, sA + ldsb + h * 2048);
#pragma unroll
    for (int h = 0; h < HB; ++h) gload_lds16(pb[h] + kk, sB + ldsb + h * 2048);
    __syncthreads();

#pragma unroll
    for (int w2 = 0; w2 < 2; ++w2) {
      bf16x8 af[RI], bfr[CJ];
#pragma unroll
      for (int i = 0; i < RI; ++i) {
        int rr = wr + (i << 4) + l15;
        int slot = ((w2 << 2) + quad - rr) & 7;
        af[i] = *(const bf16x8*)&sA[rr * BK + (slot << 3)];
      }
#pragma unroll
      for (int j = 0; j < CJ; ++j) {
        int rr = wc + (j << 4) + l15;
        int slot = ((w2 << 2) + quad - rr) & 7;
        bfr[j] = *(const bf16x8*)&sB[rr * BK + (slot << 3)];
      }
#pragma unroll
      for (int i = 0; i < RI; ++i)
#pragma unroll
        for (int j = 0; j < CJ; ++j)
          acc[i][j] = __builtin_amdgcn_mfma_f32_16x16x32_bf16(af[i], bfr[j], acc[i][j], 0, 0, 0);
    }
    __syncthreads();
  }

  // epilogue: C/D layout col=lane&15, row=quad*4+reg (verified m89/m91)
#pragma unroll
  for (int i = 0; i < RI; ++i) {
    int r0e = row0 + wr + (i << 4) + (quad << 2);
#pragma unroll
    for (int j = 0; j < CJ; ++j) {
      int gc = col0 + wc + (j << 4) + l15;
      float bb = bias ? bias[gc] : 0.0f;
#pragma unroll
      for (int r2 = 0; r2 < 4; ++r2) {
        int gr = r0e + r2;
        if (gr < M) C[(size_t)gr * N + gc] = (bf16_t)(acc[i][j][r2] + bb);
      }
    }
  }
}

// ---------------- host launch ----------------

static inline int pad8(int x) { return (x + 7) & ~7; }

extern "C" void kernel_launch(void* const* d_in, const int* in_sizes, int n_in,
                              void* d_out, int out_size, void* d_ws, size_t ws_size,
                              hipStream_t stream) {
  const float* x = (const float*)d_in[0];
  const int* ei = (const int*)d_in[1];
  const float* w0 = (const float*)d_in[2];
  const float* b0 = (const float*)d_in[3];
  const float* wsL = (const float*)d_in[4];
  const float* bsL = (const float*)d_in[5];
  const float* ln_g = (const float*)d_in[6];
  const float* ln_b = (const float*)d_in[7];
  const float* mw0 = (const float*)d_in[8];
  const float* mb0 = (const float*)d_in[9];
  const float* mg0 = (const float*)d_in[10];
  const float* mbt0 = (const float*)d_in[11];
  const float* mw1 = (const float*)d_in[12];
  const float* mb1 = (const float*)d_in[13];
  const float* mg1 = (const float*)d_in[14];
  const float* mbt1 = (const float*)d_in[15];
  const float* mw2 = (const float*)d_in[16];
  const float* mb2 = (const float*)d_in[17];
  float* out = (float*)d_out;

  char* p = (char*)d_ws;
  auto alloc = [&](size_t bytes) -> void* {
    void* r = (void*)p;
    p += (bytes + 255) & ~(size_t)255;
    return r;
  };
  float* dis = (float*)alloc((size_t)N_NODES * 4);
  int* cnt = (int*)alloc((size_t)N_NODES * 4);
  int* cursor = (int*)alloc((size_t)N_NODES * 4);
  int* rowptr = (int*)alloc((size_t)(N_NODES + 1) * 4);
  int* esrc = (int*)alloc((size_t)N_EDGES * 4);
  float* ew = (float*)alloc((size_t)N_EDGES * 4);
  bf16_t* xb = (bf16_t*)alloc((size_t)N_NODES * IN_DIM * 2);
  bf16_t* hb0 = (bf16_t*)alloc((size_t)N_NODES * HID * 2);
  bf16_t* hb1 = (bf16_t*)alloc((size_t)N_NODES * HID * 2);
  bf16_t* w0t = (bf16_t*)alloc((size_t)HID * IN_DIM * 2);
  bf16_t* wst = (bf16_t*)alloc((size_t)3 * HID * HID * 2);
  bf16_t* mw0t = (bf16_t*)alloc((size_t)2048 * 512 * 2);  // [W0_top | W0_bot] as Bt
  bf16_t* mw1t = (bf16_t*)alloc((size_t)512 * 1024 * 2);
  bf16_t* UV = (bf16_t*)alloc((size_t)N_NODES * 2048 * 2);  // 41 MB
  size_t fixed = (size_t)(p - (char*)d_ws);

  // overlap pool: GCN-phase T (10.24 MB) vs MLP z0 (2048 B/edge) + z1 (1024 B/edge).
  int CE = 16000;
  const int ce_opts[5] = {70400, 64000, 48000, 32000, 16000};  // multiples of 128
  for (int i = 0; i < 5; ++i) {
    size_t pool_need = (size_t)ce_opts[i] * 3072;
    size_t tneed = (size_t)N_NODES * HID * 2;
    if (pool_need < tneed) pool_need = tneed;
    if (fixed + pool_need + 4096 <= ws_size) { CE = ce_opts[i]; break; }
  }
  char* pool = p;
  bf16_t* T = (bf16_t*)pool;
  bf16_t* z0 = (bf16_t*)pool;  // aliases T; GCN fully precedes MLP (same stream)
  bf16_t* z1 = (bf16_t*)(pool + (size_t)CE * 2048);

  k_cast<<<(N_NODES * IN_DIM + 255) / 256, 256, 0, stream>>>(x, xb, N_NODES * IN_DIM);
  { dim3 g(HID / 32, IN_DIM / 32);
    k_tpose<<<g, 256, 0, stream>>>(w0, w0t, IN_DIM, HID); }
  for (int i = 0; i < 3; ++i) {
    dim3 g(HID / 32, HID / 32);
    k_tpose<<<g, 256, 0, stream>>>(wsL + (size_t)i * HID * HID,
                                   wst + (size_t)i * HID * HID, HID, HID);
  }
  { dim3 g(1024 / 32, 512 / 32);
    k_tpose<<<g, 256, 0, stream>>>(mw0, mw0t, 512, 1024);                       // top
    k_tpose<<<g, 256, 0, stream>>>(mw0 + (size_t)512 * 1024,
                                   mw0t + (size_t)1024 * 512, 512, 1024); }     // bot
  { dim3 g(512 / 32, 1024 / 32);
    k_tpose<<<g, 256, 0, stream>>>(mw1, mw1t, 1024, 512); }

  // CSR + degree norm (deg == cnt + 1, so one count serves both)
  k_zero2<<<(N_NODES + 255) / 256, 256, 0, stream>>>(cnt, cursor);
  k_cnt<<<(N_EDGES + 255) / 256, 256, 0, stream>>>(ei + N_EDGES, cnt);
  k_dis<<<(N_NODES + 255) / 256, 256, 0, stream>>>(cnt, dis);
  k_scan<<<1, 256, 0, stream>>>(cnt, rowptr);
  k_fill<<<(N_EDGES + 255) / 256, 256, 0, stream>>>(ei, dis, rowptr, cursor, esrc, ew);

  // ---- 4 GCN layers ----
  int nrb64 = pad8((N_NODES + 63) / 64);  // 157 -> 160
  bf16_t* hbufs[2] = {hb0, hb1};
  for (int L = 0; L < 4; ++L) {
    const bf16_t* Ain = (L == 0) ? xb : hbufs[(L + 1) & 1];
    int K = (L == 0) ? IN_DIM : HID;
    const bf16_t* Bt = (L == 0) ? w0t : wst + (size_t)(L - 1) * HID * HID;
    k_gemm<64, 128><<<nrb64 * (HID / 128), 256, 0, stream>>>(
        Ain, Bt, nullptr, T, N_NODES, HID, K, HID / 128);
    const float* bias = (L == 0) ? b0 : bsL + (size_t)(L - 1) * HID;
    k_agg_ln<<<(N_NODES + 3) / 4, 256, 0, stream>>>(
        T, rowptr, esrc, ew, dis, bias, ln_g + (size_t)L * HID,
        ln_b + (size_t)L * HID, hbufs[L & 1]);
  }
  bf16_t* hfin = hbufs[1];

  // ---- node-level UV = hfin @ [W0_top | W0_bot]  (10000 x 2048, K=512) ----
  k_gemm<64, 128><<<nrb64 * (2048 / 128), 256, 0, stream>>>(
      hfin, mw0t, nullptr, UV, N_NODES, 2048, 512, 2048 / 128);

  // ---- edge MLP, chunked (ragged last chunk OK) ----
  for (int e0 = 0; e0 < N_EDGES; ) {
    int ce = N_EDGES - e0;
    if (ce > CE) ce = CE;
    k_uv_ln<<<(ce + 7) / 8, 256, 0, stream>>>(UV, ei + e0, ei + N_EDGES + e0, mb0,
                                              mg0, mbt0, z0, ce);
    int nrb = pad8((ce + 127) / 128);
    k_gemm<128, 128><<<nrb * (HID / 128), 256, 0, stream>>>(
        z0, mw1t, mb1, z1, ce, HID, 1024, HID / 128);
    k_ln_dot<<<(ce + 7) / 8, 256, 0, stream>>>(z1, mg1, mbt1, mw2, mb2, out + e0, ce);
    e0 += ce;
  }
  (void)in_sizes; (void)n_in; (void)out_size;
}

// Round 14
// 738.442 us; speedup vs baseline: 1.5073x; 1.0503x over previous
//
#include <hip/hip_runtime.h>
#include <hip/hip_bf16.h>
#include <stdint.h>

typedef __bf16 bf16_t;
typedef bf16_t bf16x8 __attribute__((ext_vector_type(8)));
typedef float f32x4 __attribute__((ext_vector_type(4)));

#define N_NODES 10000
#define N_EDGES 160000
#define IN_DIM 128
#define HID 512
#define LN_EPS 1e-5f
#define BK 64  // 128 B per tile row: 8 x 16B chunks

#define AS1 __attribute__((address_space(1)))
#define AS3 __attribute__((address_space(3)))

static __device__ __forceinline__ void gload_lds16(const void* g, void* l) {
  __builtin_amdgcn_global_load_lds((const AS1 void*)g, (AS3 void*)l, 16, 0, 0);
}

// ---------------- prologue mega-kernel ----------------
// regions: [0,5000) cast x->xb; [5000,5040) zero cnt/cursor;
// then 6 transposes (w0t 64, wst 3x256, mw0 top 512, mw0 bot 512, mw1 512).
__global__ __launch_bounds__(256) void k_prep(
    const float* __restrict__ x, bf16_t* __restrict__ xb,
    const float* __restrict__ w0, bf16_t* __restrict__ w0t,
    const float* __restrict__ wsL, bf16_t* __restrict__ wst,
    const float* __restrict__ mw0, bf16_t* __restrict__ mw0t,
    const float* __restrict__ mw1, bf16_t* __restrict__ mw1t,
    int* __restrict__ cnt, int* __restrict__ cursor) {
  __shared__ float t[32][33];
  int bid = blockIdx.x, tid = threadIdx.x;
  if (bid < 5000) {  // cast (N_NODES*IN_DIM = 1.28M = 5000*256 exactly)
    int i = bid * 256 + tid;
    xb[i] = (bf16_t)x[i];
    return;
  }
  bid -= 5000;
  if (bid < 40) {  // zero cnt+cursor
    int i = bid * 256 + tid;
    if (i < N_NODES) { cnt[i] = 0; cursor[i] = 0; }
    return;
  }
  bid -= 40;
  const float* src;
  bf16_t* dst;
  int K, N;
  if (bid < 64) {
    src = w0; dst = w0t; K = IN_DIM; N = HID;
  } else if (bid < 64 + 768) {
    bid -= 64;
    int i = bid >> 8; bid &= 255;
    src = wsL + (size_t)i * HID * HID; dst = wst + (size_t)i * HID * HID;
    K = HID; N = HID;
  } else if (bid < 64 + 768 + 512) {
    bid -= 64 + 768;
    src = mw0; dst = mw0t; K = 512; N = 1024;                       // W0_top
  } else if (bid < 64 + 768 + 1024) {
    bid -= 64 + 768 + 512;
    src = mw0 + (size_t)512 * 1024; dst = mw0t + (size_t)1024 * 512;  // W0_bot
    K = 512; N = 1024;
  } else {
    bid -= 64 + 768 + 1024;
    src = mw1; dst = mw1t; K = 1024; N = 512;
  }
  int ncol = N >> 5;
  int bx = bid % ncol, by = bid / ncol;
  int cx = tid & 31, ry = tid >> 5;
  int n0 = bx * 32, k0 = by * 32;
#pragma unroll
  for (int i = 0; i < 32; i += 8)
    t[ry + i][cx] = src[(size_t)(k0 + ry + i) * N + n0 + cx];
  __syncthreads();
#pragma unroll
  for (int i = 0; i < 32; i += 8)
    dst[(size_t)(n0 + ry + i) * K + k0 + cx] = (bf16_t)t[cx][ry + i];
}

// ---------------- CSR build (edges keyed by target) + degree norm ----------------

__global__ void k_cnt(const int* __restrict__ key, int* cnt) {
  int e = blockIdx.x * 256 + threadIdx.x;
  if (e < N_EDGES) atomicAdd(&cnt[key[e]], 1);
}
// block 0: exclusive scan rowptr[0..N_NODES]; blocks 1..40: dis = rsqrt(cnt+1)
__global__ __launch_bounds__(256) void k_scan_dis(const int* __restrict__ cnt,
                                                  int* __restrict__ rowptr,
                                                  float* __restrict__ dis) {
  if (blockIdx.x != 0) {
    int i = (blockIdx.x - 1) * 256 + threadIdx.x;
    if (i < N_NODES) dis[i] = rsqrtf(1.0f + (float)cnt[i]);
    return;
  }
  __shared__ int part[256];
  __shared__ int pref[257];
  int tid = threadIdx.x;
  const int CH = 40;  // 256*40 >= 10001
  int s = 0;
  for (int i = 0; i < CH; ++i) {
    int idx = tid * CH + i;
    if (idx < N_NODES) s += cnt[idx];
  }
  part[tid] = s;
  __syncthreads();
  if (tid == 0) {
    int a = 0;
    for (int i = 0; i < 256; ++i) { pref[i] = a; a += part[i]; }
    pref[256] = a;
  }
  __syncthreads();
  int a = pref[tid];
  for (int i = 0; i < CH; ++i) {
    int idx = tid * CH + i;
    if (idx < N_NODES) {
      rowptr[idx] = a;
      a += cnt[idx];
    } else if (idx == N_NODES) {
      rowptr[idx] = a;
    }
  }
}
// target-CSR fill (aggregation): src + weight per slot
__global__ void k_fill(const int* __restrict__ ei, const float* __restrict__ dis,
                       const int* __restrict__ rowptr, int* __restrict__ cursor,
                       int* __restrict__ esrc, float* __restrict__ ew) {
  int e = blockIdx.x * 256 + threadIdx.x;
  if (e >= N_EDGES) return;
  int s = ei[e];
  int t = ei[N_EDGES + e];
  int pos = atomicAdd(&cursor[t], 1);
  int o = rowptr[t] + pos;
  esrc[o] = s;
  ew[o] = dis[s] * dis[t];
}

// ---------------- fused aggregation + ReLU + LayerNorm (T in bf16) ----------------
__global__ __launch_bounds__(256) void k_agg_ln(
    const bf16_t* __restrict__ T, const int* __restrict__ rowptr,
    const int* __restrict__ esrc, const float* __restrict__ ew,
    const float* __restrict__ dis, const float* __restrict__ bias,
    const float* __restrict__ g, const float* __restrict__ b,
    bf16_t* __restrict__ out) {
  int w = threadIdx.x >> 6, lane = threadIdx.x & 63;
  int node = blockIdx.x * 4 + w;
  if (node >= N_NODES) return;
  int d0 = lane << 3;  // 8 dims per lane
  float dw = dis[node];
  dw *= dw;
  float a[8];
  {
    bf16x8 tn = *(const bf16x8*)(T + (size_t)node * HID + d0);
    const f32x4* bi = (const f32x4*)(bias + d0);
    f32x4 bv0 = bi[0], bv1 = bi[1];
#pragma unroll
    for (int j = 0; j < 4; ++j) a[j] = dw * (float)tn[j] + bv0[j];
#pragma unroll
    for (int j = 0; j < 4; ++j) a[4 + j] = dw * (float)tn[4 + j] + bv1[j];
  }
  int e = rowptr[node], e1 = rowptr[node + 1];
  // 4-way unrolled gather: more loads in flight per wave (latency-bound loop)
  for (; e + 3 < e1; e += 4) {
    int s0 = esrc[e], s1i = esrc[e + 1], s2i = esrc[e + 2], s3i = esrc[e + 3];
    float w0 = ew[e], w1 = ew[e + 1], w2 = ew[e + 2], w3 = ew[e + 3];
    bf16x8 t0 = *(const bf16x8*)(T + (size_t)s0 * HID + d0);
    bf16x8 t1 = *(const bf16x8*)(T + (size_t)s1i * HID + d0);
    bf16x8 t2 = *(const bf16x8*)(T + (size_t)s2i * HID + d0);
    bf16x8 t3 = *(const bf16x8*)(T + (size_t)s3i * HID + d0);
#pragma unroll
    for (int j = 0; j < 8; ++j)
      a[j] += w0 * (float)t0[j] + w1 * (float)t1[j] + w2 * (float)t2[j] + w3 * (float)t3[j];
  }
  for (; e < e1; ++e) {
    int s0 = esrc[e];
    float w0 = ew[e];
    bf16x8 t0 = *(const bf16x8*)(T + (size_t)s0 * HID + d0);
#pragma unroll
    for (int j = 0; j < 8; ++j) a[j] += w0 * (float)t0[j];
  }
  float s1 = 0.f, s2 = 0.f;
#pragma unroll
  for (int j = 0; j < 8; ++j) {
    a[j] = fmaxf(a[j], 0.f);
    s1 += a[j];
    s2 += a[j] * a[j];
  }
#pragma unroll
  for (int off = 32; off > 0; off >>= 1) {
    s1 += __shfl_xor(s1, off);
    s2 += __shfl_xor(s2, off);
  }
  const float invD = 1.0f / (float)HID;
  float mean = s1 * invD;
  float var = s2 * invD - mean * mean;
  float inv = rsqrtf(var + LN_EPS);
  bf16_t ob[8];
#pragma unroll
  for (int j = 0; j < 8; ++j) {
    int d = d0 + j;
    ob[j] = (bf16_t)((a[j] - mean) * inv * g[d] + b[d]);
  }
  *(bf16x8*)(out + (size_t)node * HID + d0) = *(bf16x8*)ob;
}

// ---------------- per-edge MLP glue bodies (virtual-block device fns) ----------

// z0 = relu(LN(UV[src][0:1024] + UV[dst][1024:2048] + mb0)); 2 edges per wave.
static __device__ __forceinline__ void uv_ln_body(
    int vb, const bf16_t* __restrict__ UV, const int* __restrict__ srcI,
    const int* __restrict__ dstI, const float* __restrict__ mb0,
    const float* __restrict__ g, const float* __restrict__ b,
    bf16_t* __restrict__ z0, int rows) {
  int w = threadIdx.x >> 6, lane = threadIdx.x & 63;
  int row0 = vb * 8 + w * 2;  // rows always even
  if (row0 >= rows) return;
  int d0 = lane << 4;  // 16 dims per lane
  int sA = srcI[row0], tA = dstI[row0];
  int sB = srcI[row0 + 1], tB = dstI[row0 + 1];
  const bf16_t* upA = UV + (size_t)sA * 2048 + d0;
  const bf16_t* vpA = UV + (size_t)tA * 2048 + 1024 + d0;
  const bf16_t* upB = UV + (size_t)sB * 2048 + d0;
  const bf16_t* vpB = UV + (size_t)tB * 2048 + 1024 + d0;
  bf16x8 uA0 = *(const bf16x8*)upA, uA1 = *(const bf16x8*)(upA + 8);
  bf16x8 vA0 = *(const bf16x8*)vpA, vA1 = *(const bf16x8*)(vpA + 8);
  bf16x8 uB0 = *(const bf16x8*)upB, uB1 = *(const bf16x8*)(upB + 8);
  bf16x8 vB0 = *(const bf16x8*)vpB, vB1 = *(const bf16x8*)(vpB + 8);
  float fA[16], fB[16];
#pragma unroll
  for (int j = 0; j < 8; ++j) {
    float m0 = mb0[d0 + j], m1 = mb0[d0 + 8 + j];
    fA[j] = (float)uA0[j] + (float)vA0[j] + m0;
    fA[8 + j] = (float)uA1[j] + (float)vA1[j] + m1;
    fB[j] = (float)uB0[j] + (float)vB0[j] + m0;
    fB[8 + j] = (float)uB1[j] + (float)vB1[j] + m1;
  }
  float s1A = 0.f, s2A = 0.f, s1B = 0.f, s2B = 0.f;
#pragma unroll
  for (int j = 0; j < 16; ++j) {
    s1A += fA[j]; s2A += fA[j] * fA[j];
    s1B += fB[j]; s2B += fB[j] * fB[j];
  }
#pragma unroll
  for (int off = 32; off > 0; off >>= 1) {
    s1A += __shfl_xor(s1A, off); s2A += __shfl_xor(s2A, off);
    s1B += __shfl_xor(s1B, off); s2B += __shfl_xor(s2B, off);
  }
  const float invD = 1.0f / 1024.0f;
  float meanA = s1A * invD, meanB = s1B * invD;
  float invA = rsqrtf(s2A * invD - meanA * meanA + LN_EPS);
  float invB = rsqrtf(s2B * invD - meanB * meanB + LN_EPS);
  bf16_t oA0[8], oA1[8], oB0[8], oB1[8];
#pragma unroll
  for (int j = 0; j < 8; ++j) {
    float g0 = g[d0 + j], g1 = g[d0 + 8 + j];
    float b0v = b[d0 + j], b1v = b[d0 + 8 + j];
    oA0[j] = (bf16_t)fmaxf((fA[j] - meanA) * invA * g0 + b0v, 0.f);
    oA1[j] = (bf16_t)fmaxf((fA[8 + j] - meanA) * invA * g1 + b1v, 0.f);
    oB0[j] = (bf16_t)fmaxf((fB[j] - meanB) * invB * g0 + b0v, 0.f);
    oB1[j] = (bf16_t)fmaxf((fB[8 + j] - meanB) * invB * g1 + b1v, 0.f);
  }
  bf16_t* zpA = z0 + (size_t)row0 * 1024 + d0;
  bf16_t* zpB = zpA + 1024;
  *(bf16x8*)zpA = *(bf16x8*)oA0;
  *(bf16x8*)(zpA + 8) = *(bf16x8*)oA1;
  *(bf16x8*)zpB = *(bf16x8*)oB0;
  *(bf16x8*)(zpB + 8) = *(bf16x8*)oB1;
}

// out[row] = dot(relu(LN(z1[row])), mw2) + mb2; 2 rows per wave.
static __device__ __forceinline__ void ln_dot_body(
    int vb, const bf16_t* __restrict__ z1, const float* __restrict__ g,
    const float* __restrict__ b, const float* __restrict__ mw2,
    const float* __restrict__ mb2, float* __restrict__ out, int rows) {
  int w = threadIdx.x >> 6, lane = threadIdx.x & 63;
  int row0 = vb * 8 + w * 2;
  if (row0 >= rows) return;
  int d0 = lane << 3;
  bf16x8 vA = *(const bf16x8*)(z1 + (size_t)row0 * 512 + d0);
  bf16x8 vB = *(const bf16x8*)(z1 + (size_t)(row0 + 1) * 512 + d0);
  float fA[8], fB[8];
#pragma unroll
  for (int j = 0; j < 8; ++j) { fA[j] = (float)vA[j]; fB[j] = (float)vB[j]; }
  float s1A = 0.f, s2A = 0.f, s1B = 0.f, s2B = 0.f;
#pragma unroll
  for (int j = 0; j < 8; ++j) {
    s1A += fA[j]; s2A += fA[j] * fA[j];
    s1B += fB[j]; s2B += fB[j] * fB[j];
  }
#pragma unroll
  for (int off = 32; off > 0; off >>= 1) {
    s1A += __shfl_xor(s1A, off); s2A += __shfl_xor(s2A, off);
    s1B += __shfl_xor(s1B, off); s2B += __shfl_xor(s2B, off);
  }
  const float invD = 1.0f / 512.0f;
  float meanA = s1A * invD, meanB = s1B * invD;
  float invA = rsqrtf(s2A * invD - meanA * meanA + LN_EPS);
  float invB = rsqrtf(s2B * invD - meanB * meanB + LN_EPS);
  float accA = 0.f, accB = 0.f;
#pragma unroll
  for (int j = 0; j < 8; ++j) {
    float gv = g[d0 + j], bv = b[d0 + j], wv = mw2[d0 + j];
    accA += fmaxf((fA[j] - meanA) * invA * gv + bv, 0.f) * wv;
    accB += fmaxf((fB[j] - meanB) * invB * gv + bv, 0.f) * wv;
  }
#pragma unroll
  for (int off = 32; off > 0; off >>= 1) {
    accA += __shfl_xor(accA, off);
    accB += __shfl_xor(accB, off);
  }
  if (lane == 0) {
    out[row0] = accA + mb2[0];
    out[row0 + 1] = accB + mb2[0];
  }
}

__global__ __launch_bounds__(256) void k_uv_ln(
    const bf16_t* UV, const int* srcI, const int* dstI, const float* mb0,
    const float* g, const float* b, bf16_t* z0, int rows) {
  uv_ln_body(blockIdx.x, UV, srcI, dstI, mb0, g, b, z0, rows);
}
__global__ __launch_bounds__(256) void k_ln_dot(
    const bf16_t* z1, const float* g, const float* b, const float* mw2,
    const float* mb2, float* out, int rows) {
  ln_dot_body(blockIdx.x, z1, g, b, mw2, mb2, out, rows);
}
// merged: ln_dot for chunk c (blocks [0,nld)) + uv_ln for chunk c+1 (rest)
__global__ __launch_bounds__(256) void k_ld_uv(
    const bf16_t* z1, const float* lg, const float* lb, const float* mw2,
    const float* mb2, float* outc, int rows_ld,
    const bf16_t* UV, const int* srcI, const int* dstI, const float* mb0,
    const float* ug, const float* ub, bf16_t* z0, int rows_uv) {
  int nld = (rows_ld + 7) / 8;
  if ((int)blockIdx.x < nld)
    ln_dot_body(blockIdx.x, z1, lg, lb, mw2, mb2, outc, rows_ld);
  else
    uv_ln_body(blockIdx.x - nld, UV, srcI, dstI, mb0, ug, ub, z0, rows_uv);
}

// ---------------- streaming GEMM, BK=64, single-buffered ------------------------
// C[M x N] = bf16(A @ Bt^T + bias). 1D grid, temporally-L2-aware XCD decode:
//   id = xcd + 8*(col + ncol*rowgroup), rb = rowgroup*8 + xcd.
// The ncol col-tiles of one row-block land on the SAME XCD at ids differing by 8
// (temporally adjacent) -> A-tile fetched once into that XCD's L2, reused ncol x.
// LDS row = 128 B (8 x 16B slots). Slot s of row r holds global k-chunk (s+r)&7;
// fragment read of chunk c hits slot (c-r)&7 -> 2-way bank aliasing = free.
template <int BMt, int BNt>
__global__ __launch_bounds__(256) void k_gemm(
    const bf16_t* __restrict__ A, const bf16_t* __restrict__ Bt,
    const float* __restrict__ bias, bf16_t* __restrict__ C,
    int M, int N, int K, int ncol) {
  constexpr int RI = BMt / 32, CJ = BNt / 32;
  constexpr int HA = BMt / 32, HB = BNt / 32;
  __shared__ __align__(16) bf16_t sA[BMt * BK];
  __shared__ __align__(16) bf16_t sB[BNt * BK];

  int tid = threadIdx.x;
  int bid = blockIdx.x;
  int xcd = bid & 7;
  int rest = bid >> 3;
  int col = rest % ncol;
  int rb = ((rest / ncol) << 3) + xcd;
  int row0 = rb * BMt, col0 = col * BNt;
  if (row0 >= M) return;  // padded row-blocks
  int lane = tid & 63, w = tid >> 6;
  int quad = lane >> 4, l15 = lane & 15;
  int wr = (w >> 1) * (BMt / 2), wc = (w & 1) * (BNt / 2);

  int rbase = tid >> 3;                       // row within 32-row staging step
  int gk = ((tid & 7) + rbase) & 7;           // rotated global k-chunk
  int ksegg = gk << 3;

  const bf16_t* pa[HA];
  const bf16_t* pb[HB];
#pragma unroll
  for (int h = 0; h < HA; ++h) {
    int g0 = row0 + rbase + h * 32;
    if (g0 >= M) g0 = M - 1;  // clamp; never stored
    pa[h] = A + (size_t)g0 * K;
  }
#pragma unroll
  for (int h = 0; h < HB; ++h)
    pb[h] = Bt + (size_t)(col0 + rbase + h * 32) * K;

  int ldsb = (tid & ~63) * 8;

  f32x4 acc[RI][CJ] = {};

  for (int k0 = 0; k0 < K; k0 += BK) {
    int kk = k0 + ksegg;
#pragma unroll
    for (int h = 0; h < HA; ++h) gload_lds16(pa[h] + kk, sA + ldsb + h * 2048);
#pragma unroll
    for (int h = 0; h < HB; ++h) gload_lds16(pb[h] + kk, sB + ldsb + h * 2048);
    __syncthreads();

#pragma unroll
    for (int w2 = 0; w2 < 2; ++w2) {
      bf16x8 af[RI], bfr[CJ];
#pragma unroll
      for (int i = 0; i < RI; ++i) {
        int rr = wr + (i << 4) + l15;
        int slot = ((w2 << 2) + quad - rr) & 7;
        af[i] = *(const bf16x8*)&sA[rr * BK + (slot << 3)];
      }
#pragma unroll
      for (int j = 0; j < CJ; ++j) {
        int rr = wc + (j << 4) + l15;
        int slot = ((w2 << 2) + quad - rr) & 7;
        bfr[j] = *(const bf16x8*)&sB[rr * BK + (slot << 3)];
      }
#pragma unroll
      for (int i = 0; i < RI; ++i)
#pragma unroll
        for (int j = 0; j < CJ; ++j)
          acc[i][j] = __builtin_amdgcn_mfma_f32_16x16x32_bf16(af[i], bfr[j], acc[i][j], 0, 0, 0);
    }
    __syncthreads();
  }

  // epilogue: C/D layout col=lane&15, row=quad*4+reg (verified m89/m91)
#pragma unroll
  for (int i = 0; i < RI; ++i) {
    int r0e = row0 + wr + (i << 4) + (quad << 2);
#pragma unroll
    for (int j = 0; j < CJ; ++j) {
      int gc = col0 + wc + (j << 4) + l15;
      float bb = bias ? bias[gc] : 0.0f;
#pragma unroll
      for (int r2 = 0; r2 < 4; ++r2) {
        int gr = r0e + r2;
        if (gr < M) C[(size_t)gr * N + gc] = (bf16_t)(acc[i][j][r2] + bb);
      }
    }
  }
}

// ---------------- host launch ----------------

static inline int pad8(int x) { return (x + 7) & ~7; }

extern "C" void kernel_launch(void* const* d_in, const int* in_sizes, int n_in,
                              void* d_out, int out_size, void* d_ws, size_t ws_size,
                              hipStream_t stream) {
  const float* x = (const float*)d_in[0];
  const int* ei = (const int*)d_in[1];
  const float* w0 = (const float*)d_in[2];
  const float* b0 = (const float*)d_in[3];
  const float* wsL = (const float*)d_in[4];
  const float* bsL = (const float*)d_in[5];
  const float* ln_g = (const float*)d_in[6];
  const float* ln_b = (const float*)d_in[7];
  const float* mw0 = (const float*)d_in[8];
  const float* mb0 = (const float*)d_in[9];
  const float* mg0 = (const float*)d_in[10];
  const float* mbt0 = (const float*)d_in[11];
  const float* mw1 = (const float*)d_in[12];
  const float* mb1 = (const float*)d_in[13];
  const float* mg1 = (const float*)d_in[14];
  const float* mbt1 = (const float*)d_in[15];
  const float* mw2 = (const float*)d_in[16];
  const float* mb2 = (const float*)d_in[17];
  float* out = (float*)d_out;

  char* p = (char*)d_ws;
  auto alloc = [&](size_t bytes) -> void* {
    void* r = (void*)p;
    p += (bytes + 255) & ~(size_t)255;
    return r;
  };
  float* dis = (float*)alloc((size_t)N_NODES * 4);
  int* cnt = (int*)alloc((size_t)N_NODES * 4);
  int* cursor = (int*)alloc((size_t)N_NODES * 4);
  int* rowptr = (int*)alloc((size_t)(N_NODES + 1) * 4);
  int* esrc = (int*)alloc((size_t)N_EDGES * 4);
  float* ew = (float*)alloc((size_t)N_EDGES * 4);
  bf16_t* xb = (bf16_t*)alloc((size_t)N_NODES * IN_DIM * 2);
  bf16_t* hb0 = (bf16_t*)alloc((size_t)N_NODES * HID * 2);
  bf16_t* hb1 = (bf16_t*)alloc((size_t)N_NODES * HID * 2);
  bf16_t* w0t = (bf16_t*)alloc((size_t)HID * IN_DIM * 2);
  bf16_t* wst = (bf16_t*)alloc((size_t)3 * HID * HID * 2);
  bf16_t* mw0t = (bf16_t*)alloc((size_t)2048 * 512 * 2);  // [W0_top | W0_bot] as Bt
  bf16_t* mw1t = (bf16_t*)alloc((size_t)512 * 1024 * 2);
  bf16_t* UV = (bf16_t*)alloc((size_t)N_NODES * 2048 * 2);  // 41 MB
  size_t fixed = (size_t)(p - (char*)d_ws);

  // overlap pool: GCN-phase T (10.24 MB) vs MLP z0 (2048 B/edge) + z1 (1024 B/edge).
  int CE = 16000;
  const int ce_opts[5] = {70400, 64000, 48000, 32000, 16000};  // even, mult of 128
  for (int i = 0; i < 5; ++i) {
    size_t pool_need = (size_t)ce_opts[i] * 3072;
    size_t tneed = (size_t)N_NODES * HID * 2;
    if (pool_need < tneed) pool_need = tneed;
    if (fixed + pool_need + 4096 <= ws_size) { CE = ce_opts[i]; break; }
  }
  char* pool = p;
  bf16_t* T = (bf16_t*)pool;
  bf16_t* z0 = (bf16_t*)pool;  // aliases T; GCN fully precedes MLP (same stream)
  bf16_t* z1 = (bf16_t*)(pool + (size_t)CE * 2048);

  // ---- prologue: one mega-dispatch (cast + zero + 6 transposes), then CSR ----
  k_prep<<<5000 + 40 + 64 + 768 + 1536, 256, 0, stream>>>(
      x, xb, w0, w0t, wsL, wst, mw0, mw0t, mw1, mw1t, cnt, cursor);
  k_cnt<<<(N_EDGES + 255) / 256, 256, 0, stream>>>(ei + N_EDGES, cnt);
  k_scan_dis<<<41, 256, 0, stream>>>(cnt, rowptr, dis);
  k_fill<<<(N_EDGES + 255) / 256, 256, 0, stream>>>(ei, dis, rowptr, cursor, esrc, ew);

  // ---- 4 GCN layers ----
  int nrb64 = pad8((N_NODES + 63) / 64);  // 157 -> 160
  bf16_t* hbufs[2] = {hb0, hb1};
  for (int L = 0; L < 4; ++L) {
    const bf16_t* Ain = (L == 0) ? xb : hbufs[(L + 1) & 1];
    int K = (L == 0) ? IN_DIM : HID;
    const bf16_t* Bt = (L == 0) ? w0t : wst + (size_t)(L - 1) * HID * HID;
    k_gemm<64, 128><<<nrb64 * (HID / 128), 256, 0, stream>>>(
        Ain, Bt, nullptr, T, N_NODES, HID, K, HID / 128);
    const float* bias = (L == 0) ? b0 : bsL + (size_t)(L - 1) * HID;
    k_agg_ln<<<(N_NODES + 3) / 4, 256, 0, stream>>>(
        T, rowptr, esrc, ew, dis, bias, ln_g + (size_t)L * HID,
        ln_b + (size_t)L * HID, hbufs[L & 1]);
  }
  bf16_t* hfin = hbufs[1];

  // ---- node-level UV = hfin @ [W0_top | W0_bot]  (10000 x 2048, K=512) ----
  k_gemm<64, 128><<<nrb64 * (2048 / 128), 256, 0, stream>>>(
      hfin, mw0t, nullptr, UV, N_NODES, 2048, 512, 2048 / 128);

  // ---- edge MLP, chunked; ln_dot(c) merged with uv_ln(c+1) ----
  int e0s[16], ces[16], nch = 0;
  for (int e0 = 0; e0 < N_EDGES;) {
    int ce = N_EDGES - e0;
    if (ce > CE) ce = CE;
    e0s[nch] = e0; ces[nch] = ce; ++nch;
    e0 += ce;
  }
  k_uv_ln<<<(ces[0] + 7) / 8, 256, 0, stream>>>(
      UV, ei + e0s[0], ei + N_EDGES + e0s[0], mb0, mg0, mbt0, z0, ces[0]);
  for (int c = 0; c < nch; ++c) {
    int nrb = pad8((ces[c] + 127) / 128);
    k_gemm<128, 128><<<nrb * (HID / 128), 256, 0, stream>>>(
        z0, mw1t, mb1, z1, ces[c], HID, 1024, HID / 128);
    if (c + 1 < nch) {
      int nld = (ces[c] + 7) / 8, nuv = (ces[c + 1] + 7) / 8;
      k_ld_uv<<<nld + nuv, 256, 0, stream>>>(
          z1, mg1, mbt1, mw2, mb2, out + e0s[c], ces[c],
          UV, ei + e0s[c + 1], ei + N_EDGES + e0s[c + 1], mb0, mg0, mbt0,
          z0, ces[c + 1]);
    } else {
      k_ln_dot<<<(ces[c] + 7) / 8, 256, 0, stream>>>(
          z1, mg1, mbt1, mw2, mb2, out + e0s[c], ces[c]);
    }
  }
  (void)in_sizes; (void)n_in; (void)out_size;
}